// Round 1
// baseline (3105.354 us; speedup 1.0000x reference)
//
#include <hip/hip_runtime.h>

#define NUM_USER 100000
#define NUM_ITEM 50000
#define NUM_NODES 150000
#define FEAT_DIM 512
#define DLAT 64
#define HID 256

typedef float f32x4 __attribute__((ext_vector_type(4)));
typedef __bf16 bf16x8 __attribute__((ext_vector_type(8)));
typedef unsigned short ushort8v __attribute__((ext_vector_type(8)));

union BF8 { ushort8v u; bf16x8 b; };

__device__ inline unsigned short f2bf_rne(float f) {
    unsigned u = __float_as_uint(f);
    u += 0x7FFFu + ((u >> 16) & 1u);
    return (unsigned short)(u >> 16);
}

// ---------------- degree / norm ----------------
__global__ void deg_kernel(const int* __restrict__ src, int* __restrict__ deg, int E) {
    int i = blockIdx.x * blockDim.x + threadIdx.x;
    if (i < E) atomicAdd(&deg[src[i]], 1);
}

__global__ void dinv_kernel(const int* __restrict__ deg, float* __restrict__ dinv, int n) {
    int i = blockIdx.x * blockDim.x + threadIdx.x;
    if (i < n) {
        int d = deg[i];
        dinv[i] = d > 0 ? rsqrtf((float)d) : 0.0f;
    }
}

// ---------------- weight conversion (transpose to bf16) ----------------
__global__ void convert_weights(const float* __restrict__ W1, const float* __restrict__ W2,
                                unsigned short* __restrict__ w1t, unsigned short* __restrict__ w2t) {
    int idx = blockIdx.x * blockDim.x + threadIdx.x;
    if (idx < FEAT_DIM * HID) {
        int k = idx / HID, n = idx % HID;          // W1[k][n]
        w1t[(size_t)n * FEAT_DIM + k] = f2bf_rne(W1[idx]);
    } else {
        int j = idx - FEAT_DIM * HID;
        if (j < HID * DLAT) {
            int k = j / DLAT, n = j % DLAT;        // W2[k][n]
            w2t[(size_t)n * HID + k] = f2bf_rne(W2[j]);
        }
    }
}

// ---------------- fused item MLP: bf16 MFMA ----------------
// Block: 256 threads (4 waves), 64 items per block.
// GEMM1: [64x512] x [512x256] -> LeakyReLU -> LDS (bf16)
// GEMM2: [64x256] x [256x64]  -> xout rows NUM_USER+item
__launch_bounds__(256)
__global__ void mlp_kernel(const float* __restrict__ feats,
                           const unsigned short* __restrict__ w1t, // [256][512] bf16
                           const unsigned short* __restrict__ w2t, // [64][256] bf16
                           const float* __restrict__ b1,
                           const float* __restrict__ b2,
                           float* __restrict__ xout) {
    __shared__ unsigned short sH[64][264];  // +8 pad => row stride 528B (16B aligned, bank-spread)

    const int tid  = threadIdx.x;
    const int lane = tid & 63;
    const int w    = tid >> 6;      // wave 0..3
    const int wr   = w >> 1;        // wave row 0..1 (32 rows each)
    const int wc   = w & 1;         // wave col 0..1 (128 cols each)
    const int l15  = lane & 15;
    const int l4   = lane >> 4;     // 0..3
    const int item0 = blockIdx.x * 64;

    f32x4 acc[2][8];
    #pragma unroll
    for (int i = 0; i < 2; ++i)
        #pragma unroll
        for (int j = 0; j < 8; ++j) acc[i][j] = (f32x4)0.0f;

    // ---- GEMM1: K = 512 in 16 steps of 32 ----
    for (int kk = 0; kk < 16; ++kk) {
        const int kbase = kk * 32 + l4 * 8;
        bf16x8 afrag[2];
        #pragma unroll
        for (int rf = 0; rf < 2; ++rf) {
            int row = item0 + wr * 32 + rf * 16 + l15;
            row = min(row, NUM_ITEM - 1);
            const float4* ap = reinterpret_cast<const float4*>(feats + (size_t)row * FEAT_DIM + kbase);
            float4 x0 = ap[0], x1 = ap[1];
            BF8 t;
            t.u[0] = f2bf_rne(x0.x); t.u[1] = f2bf_rne(x0.y);
            t.u[2] = f2bf_rne(x0.z); t.u[3] = f2bf_rne(x0.w);
            t.u[4] = f2bf_rne(x1.x); t.u[5] = f2bf_rne(x1.y);
            t.u[6] = f2bf_rne(x1.z); t.u[7] = f2bf_rne(x1.w);
            afrag[rf] = t.b;
        }
        #pragma unroll
        for (int cf = 0; cf < 8; ++cf) {
            int col = wc * 128 + cf * 16 + l15;
            BF8 t;
            t.u = *reinterpret_cast<const ushort8v*>(w1t + (size_t)col * FEAT_DIM + kbase);
            acc[0][cf] = __builtin_amdgcn_mfma_f32_16x16x32_bf16(afrag[0], t.b, acc[0][cf], 0, 0, 0);
            acc[1][cf] = __builtin_amdgcn_mfma_f32_16x16x32_bf16(afrag[1], t.b, acc[1][cf], 0, 0, 0);
        }
    }

    // ---- bias + LeakyReLU -> LDS bf16 ----
    #pragma unroll
    for (int rf = 0; rf < 2; ++rf) {
        #pragma unroll
        for (int cf = 0; cf < 8; ++cf) {
            int col = wc * 128 + cf * 16 + l15;
            float bias = b1[col];
            #pragma unroll
            for (int r = 0; r < 4; ++r) {
                int lrow = wr * 32 + rf * 16 + l4 * 4 + r;
                float h = acc[rf][cf][r] + bias;
                h = h > 0.0f ? h : 0.01f * h;
                sH[lrow][col] = f2bf_rne(h);
            }
        }
    }
    __syncthreads();

    // ---- GEMM2: wave w computes rows w*16..w*16+15, cols 0..63 ----
    f32x4 acc2[4];
    #pragma unroll
    for (int j = 0; j < 4; ++j) acc2[j] = (f32x4)0.0f;

    for (int kk = 0; kk < 8; ++kk) {
        const int kbase = kk * 32 + l4 * 8;
        BF8 ta;
        ta.u = *reinterpret_cast<const ushort8v*>(&sH[w * 16 + l15][kbase]);
        #pragma unroll
        for (int cf = 0; cf < 4; ++cf) {
            int col = cf * 16 + l15;
            BF8 tb;
            tb.u = *reinterpret_cast<const ushort8v*>(w2t + (size_t)col * HID + kbase);
            acc2[cf] = __builtin_amdgcn_mfma_f32_16x16x32_bf16(ta.b, tb.b, acc2[cf], 0, 0, 0);
        }
    }

    #pragma unroll
    for (int cf = 0; cf < 4; ++cf) {
        int col = cf * 16 + l15;
        float bias = b2[col];
        #pragma unroll
        for (int r = 0; r < 4; ++r) {
            int item = item0 + w * 16 + l4 * 4 + r;
            if (item < NUM_ITEM) {
                xout[(size_t)(NUM_USER + item) * DLAT + col] = acc2[cf][r] + bias;
            }
        }
    }
}

// ---------------- propagation hop: one wave per edge, lane = dim ----------------
__launch_bounds__(256)
__global__ void hop_kernel(const int* __restrict__ src, const int* __restrict__ dst,
                           const float* __restrict__ dinv,
                           const float* __restrict__ xin, float* __restrict__ xout,
                           int E) {
    const int lane  = threadIdx.x & 63;
    const int wave  = (blockIdx.x * blockDim.x + threadIdx.x) >> 6;
    const int nwave = (gridDim.x * blockDim.x) >> 6;
    for (int e = wave; e < E; e += nwave) {
        int s = src[e];
        int d = dst[e];
        float nv = dinv[s] * dinv[d];
        float v  = xin[(size_t)d * DLAT + lane] * nv;
        atomicAdd(&xout[(size_t)s * DLAT + lane], v);
    }
}

// ---------------- accumulation ----------------
__global__ void add_kernel(float* __restrict__ out, const float* __restrict__ x, int n4) {
    int i = blockIdx.x * blockDim.x + threadIdx.x;
    if (i < n4) {
        float4 a = reinterpret_cast<float4*>(out)[i];
        float4 b = reinterpret_cast<const float4*>(x)[i];
        a.x += b.x; a.y += b.y; a.z += b.z; a.w += b.w;
        reinterpret_cast<float4*>(out)[i] = a;
    }
}

__global__ void final_kernel(float* __restrict__ out, const float* __restrict__ x, int n4) {
    const float s = 1.0f / 3.0f;
    int i = blockIdx.x * blockDim.x + threadIdx.x;
    if (i < n4) {
        float4 a = reinterpret_cast<float4*>(out)[i];
        float4 b = reinterpret_cast<const float4*>(x)[i];
        a.x = (a.x + b.x) * s; a.y = (a.y + b.y) * s;
        a.z = (a.z + b.z) * s; a.w = (a.w + b.w) * s;
        reinterpret_cast<float4*>(out)[i] = a;
    }
}

extern "C" void kernel_launch(void* const* d_in, const int* in_sizes, int n_in,
                              void* d_out, int out_size, void* d_ws, size_t ws_size,
                              hipStream_t stream) {
    const float* feats = (const float*)d_in[0];
    const int*   eidx  = (const int*)d_in[1];
    const float* pref  = (const float*)d_in[2];
    const float* W1    = (const float*)d_in[3];
    const float* b1    = (const float*)d_in[4];
    const float* W2    = (const float*)d_in[5];
    const float* b2    = (const float*)d_in[6];

    const int E = in_sizes[1] / 2;
    const int* src = eidx;
    const int* dst = eidx + E;

    char* ws = (char*)d_ws;
    size_t off = 0;
    auto alloc = [&](size_t bytes) -> void* {
        void* p = ws + off;
        off += (bytes + 255) & ~(size_t)255;
        return p;
    };
    const size_t xbytes = (size_t)NUM_NODES * DLAT * sizeof(float);
    float* xa = (float*)alloc(xbytes);
    float* xb = (float*)alloc(xbytes);
    int*   deg = (int*)alloc((size_t)NUM_NODES * sizeof(int));
    float* dinv = (float*)alloc((size_t)NUM_NODES * sizeof(float));
    unsigned short* w1t = (unsigned short*)alloc((size_t)FEAT_DIM * HID * 2);
    unsigned short* w2t = (unsigned short*)alloc((size_t)HID * DLAT * 2);
    float* out = (float*)d_out;

    const int n4 = NUM_NODES * DLAT / 4;

    // degrees + normalization
    hipMemsetAsync(deg, 0, (size_t)NUM_NODES * sizeof(int), stream);
    deg_kernel<<<(E + 255) / 256, 256, 0, stream>>>(src, deg, E);
    dinv_kernel<<<(NUM_NODES + 255) / 256, 256, 0, stream>>>(deg, dinv, NUM_NODES);

    // weights -> bf16 transposed
    convert_weights<<<(FEAT_DIM * HID + HID * DLAT + 255) / 256, 256, 0, stream>>>(W1, W2, w1t, w2t);

    // item MLP -> xa[NUM_USER:], preference -> xa[:NUM_USER]
    mlp_kernel<<<(NUM_ITEM + 63) / 64, 256, 0, stream>>>(feats, w1t, w2t, b1, b2, xa);
    hipMemcpyAsync(xa, pref, (size_t)NUM_USER * DLAT * sizeof(float),
                   hipMemcpyDeviceToDevice, stream);

    // acc = x0
    hipMemcpyAsync(d_out, xa, xbytes, hipMemcpyDeviceToDevice, stream);

    // hop 1: xb = A xa ; acc += xb
    hipMemsetAsync(xb, 0, xbytes, stream);
    hop_kernel<<<4096, 256, 0, stream>>>(src, dst, dinv, xa, xb, E);
    add_kernel<<<(n4 + 255) / 256, 256, 0, stream>>>(out, xb, n4);

    // hop 2: xa = A xb ; acc = (acc + xa) / 3
    hipMemsetAsync(xa, 0, xbytes, stream);
    hop_kernel<<<4096, 256, 0, stream>>>(src, dst, dinv, xb, xa, E);
    final_kernel<<<(n4 + 255) / 256, 256, 0, stream>>>(out, xa, n4);
}

// Round 2
// 1402.978 us; speedup vs baseline: 2.2134x; 2.2134x over previous
//
#include <hip/hip_runtime.h>

#define NUM_USER 100000
#define NUM_ITEM 50000
#define NUM_NODES 150000
#define FEAT_DIM 512
#define DLAT 64
#define HID 256

typedef float f32x4 __attribute__((ext_vector_type(4)));
typedef __bf16 bf16x8 __attribute__((ext_vector_type(8)));
typedef unsigned short ushort8v __attribute__((ext_vector_type(8)));

union BF8 { ushort8v u; bf16x8 b; };

__device__ inline unsigned short f2bf_rne(float f) {
    unsigned u = __float_as_uint(f);
    u += 0x7FFFu + ((u >> 16) & 1u);
    return (unsigned short)(u >> 16);
}

// ---------------- degree ----------------
__global__ void deg_kernel(const int* __restrict__ src, int* __restrict__ deg, int E) {
    int i = blockIdx.x * blockDim.x + threadIdx.x;
    if (i < E) atomicAdd(&deg[src[i]], 1);
}

__global__ void dinv_kernel(const int* __restrict__ deg, float* __restrict__ dinv, int n) {
    int i = blockIdx.x * blockDim.x + threadIdx.x;
    if (i < n) {
        int d = deg[i];
        dinv[i] = d > 0 ? rsqrtf((float)d) : 0.0f;
    }
}

// ---------------- hierarchical exclusive scan for rowptr ----------------
__global__ void scan_partial(const int* __restrict__ deg, int* __restrict__ partial, int n) {
    __shared__ int sdata[256];
    int t = threadIdx.x;
    int i = blockIdx.x * 256 + t;
    sdata[t] = (i < n) ? deg[i] : 0;
    __syncthreads();
    for (int s = 128; s > 0; s >>= 1) {
        if (t < s) sdata[t] += sdata[t + s];
        __syncthreads();
    }
    if (t == 0) partial[blockIdx.x] = sdata[0];
}

__global__ void scan_offsets(int* __restrict__ partial, int nb) {
    __shared__ int s[1024];
    int t = threadIdx.x;
    s[t] = (t < nb) ? partial[t] : 0;
    __syncthreads();
    for (int off = 1; off < 1024; off <<= 1) {
        int add = (t >= off) ? s[t - off] : 0;
        __syncthreads();
        s[t] += add;
        __syncthreads();
    }
    if (t < nb) partial[t] = (t == 0) ? 0 : s[t - 1];  // exclusive
}

__global__ void scan_rowptr(const int* __restrict__ deg, const int* __restrict__ blockoff,
                            int* __restrict__ rowptr, int n) {
    __shared__ int s[256];
    int t = threadIdx.x;
    int i = blockIdx.x * 256 + t;
    int v = (i < n) ? deg[i] : 0;
    s[t] = v;
    __syncthreads();
    for (int off = 1; off < 256; off <<= 1) {
        int add = (t >= off) ? s[t - off] : 0;
        __syncthreads();
        s[t] += add;
        __syncthreads();
    }
    int incl = s[t];
    int base = blockoff[blockIdx.x];
    if (i < n) {
        rowptr[i] = base + incl - v;
        if (i == n - 1) rowptr[n] = base + incl;
    }
}

// ---------------- CSR fill ----------------
__global__ void fill_csr(const int* __restrict__ src, const int* __restrict__ dst,
                         const int* __restrict__ rowptr, int* __restrict__ cnt,
                         int* __restrict__ col, int E) {
    int i = blockIdx.x * blockDim.x + threadIdx.x;
    if (i < E) {
        int s = src[i];
        int pos = atomicAdd(&cnt[s], 1);
        col[rowptr[s] + pos] = dst[i];
    }
}

// ---------------- weight conversion (transpose to bf16) ----------------
__global__ void convert_weights(const float* __restrict__ W1, const float* __restrict__ W2,
                                unsigned short* __restrict__ w1t, unsigned short* __restrict__ w2t) {
    int idx = blockIdx.x * blockDim.x + threadIdx.x;
    if (idx < FEAT_DIM * HID) {
        int k = idx / HID, n = idx % HID;
        w1t[(size_t)n * FEAT_DIM + k] = f2bf_rne(W1[idx]);
    } else {
        int j = idx - FEAT_DIM * HID;
        if (j < HID * DLAT) {
            int k = j / DLAT, n = j % DLAT;
            w2t[(size_t)n * HID + k] = f2bf_rne(W2[j]);
        }
    }
}

// ---------------- fused item MLP: bf16 MFMA ----------------
__launch_bounds__(256)
__global__ void mlp_kernel(const float* __restrict__ feats,
                           const unsigned short* __restrict__ w1t,
                           const unsigned short* __restrict__ w2t,
                           const float* __restrict__ b1,
                           const float* __restrict__ b2,
                           const float* __restrict__ dinv,
                           float* __restrict__ out,
                           float* __restrict__ xs) {
    __shared__ unsigned short sH[64][264];

    const int tid  = threadIdx.x;
    const int lane = tid & 63;
    const int w    = tid >> 6;
    const int wr   = w >> 1;
    const int wc   = w & 1;
    const int l15  = lane & 15;
    const int l4   = lane >> 4;
    const int item0 = blockIdx.x * 64;

    f32x4 acc[2][8];
    #pragma unroll
    for (int i = 0; i < 2; ++i)
        #pragma unroll
        for (int j = 0; j < 8; ++j) acc[i][j] = (f32x4)0.0f;

    for (int kk = 0; kk < 16; ++kk) {
        const int kbase = kk * 32 + l4 * 8;
        bf16x8 afrag[2];
        #pragma unroll
        for (int rf = 0; rf < 2; ++rf) {
            int row = item0 + wr * 32 + rf * 16 + l15;
            row = min(row, NUM_ITEM - 1);
            const float4* ap = reinterpret_cast<const float4*>(feats + (size_t)row * FEAT_DIM + kbase);
            float4 x0 = ap[0], x1 = ap[1];
            BF8 t;
            t.u[0] = f2bf_rne(x0.x); t.u[1] = f2bf_rne(x0.y);
            t.u[2] = f2bf_rne(x0.z); t.u[3] = f2bf_rne(x0.w);
            t.u[4] = f2bf_rne(x1.x); t.u[5] = f2bf_rne(x1.y);
            t.u[6] = f2bf_rne(x1.z); t.u[7] = f2bf_rne(x1.w);
            afrag[rf] = t.b;
        }
        #pragma unroll
        for (int cf = 0; cf < 8; ++cf) {
            int colc = wc * 128 + cf * 16 + l15;
            BF8 t;
            t.u = *reinterpret_cast<const ushort8v*>(w1t + (size_t)colc * FEAT_DIM + kbase);
            acc[0][cf] = __builtin_amdgcn_mfma_f32_16x16x32_bf16(afrag[0], t.b, acc[0][cf], 0, 0, 0);
            acc[1][cf] = __builtin_amdgcn_mfma_f32_16x16x32_bf16(afrag[1], t.b, acc[1][cf], 0, 0, 0);
        }
    }

    #pragma unroll
    for (int rf = 0; rf < 2; ++rf) {
        #pragma unroll
        for (int cf = 0; cf < 8; ++cf) {
            int colc = wc * 128 + cf * 16 + l15;
            float bias = b1[colc];
            #pragma unroll
            for (int r = 0; r < 4; ++r) {
                int lrow = wr * 32 + rf * 16 + l4 * 4 + r;
                float h = acc[rf][cf][r] + bias;
                h = h > 0.0f ? h : 0.01f * h;
                sH[lrow][colc] = f2bf_rne(h);
            }
        }
    }
    __syncthreads();

    f32x4 acc2[4];
    #pragma unroll
    for (int j = 0; j < 4; ++j) acc2[j] = (f32x4)0.0f;

    for (int kk = 0; kk < 8; ++kk) {
        const int kbase = kk * 32 + l4 * 8;
        BF8 ta;
        ta.u = *reinterpret_cast<const ushort8v*>(&sH[w * 16 + l15][kbase]);
        #pragma unroll
        for (int cf = 0; cf < 4; ++cf) {
            int colc = cf * 16 + l15;
            BF8 tb;
            tb.u = *reinterpret_cast<const ushort8v*>(w2t + (size_t)colc * HID + kbase);
            acc2[cf] = __builtin_amdgcn_mfma_f32_16x16x32_bf16(ta.b, tb.b, acc2[cf], 0, 0, 0);
        }
    }

    #pragma unroll
    for (int cf = 0; cf < 4; ++cf) {
        int colc = cf * 16 + l15;
        float bias = b2[colc];
        #pragma unroll
        for (int r = 0; r < 4; ++r) {
            int item = item0 + w * 16 + l4 * 4 + r;
            if (item < NUM_ITEM) {
                int node = NUM_USER + item;
                float v = acc2[cf][r] + bias;
                out[(size_t)node * DLAT + colc] = v;
                xs [(size_t)node * DLAT + colc] = v * dinv[node];
            }
        }
    }
}

// ---------------- user init: out = pref, xs = pref * dinv ----------------
__global__ void pref_init(const float* __restrict__ pref, const float* __restrict__ dinv,
                          float* __restrict__ out, float* __restrict__ xs, int n4) {
    int i = blockIdx.x * blockDim.x + threadIdx.x;  // float4 index over NUM_USER*64/4
    if (i < n4) {
        float4 v = reinterpret_cast<const float4*>(pref)[i];
        float di = dinv[i >> 4];
        reinterpret_cast<float4*>(out)[i] = v;
        float4 s;
        s.x = v.x * di; s.y = v.y * di; s.z = v.z * di; s.w = v.w * di;
        reinterpret_cast<float4*>(xs)[i] = s;
    }
}

// ---------------- CSR gather hop: one wave per node, lane = dim ----------------
__launch_bounds__(256)
__global__ void hop_csr(const int* __restrict__ rowptr, const int* __restrict__ col,
                        const float* __restrict__ dinv, const float* __restrict__ xs,
                        float* __restrict__ out, float* __restrict__ xs_next,
                        int is_final, int n) {
    const int wave = (blockIdx.x * blockDim.x + threadIdx.x) >> 6;
    const int lane = threadIdx.x & 63;
    if (wave >= n) return;
    const int s  = wave;
    const int r0 = rowptr[s];
    const int r1 = rowptr[s + 1];

    float sum = 0.0f;
    for (int base = r0; base < r1; base += 64) {
        int rem = r1 - base;
        int c = (lane < rem) ? col[base + lane] : 0;
        int m = rem < 64 ? rem : 64;
        for (int j = 0; j < m; ++j) {
            int cj = __shfl(c, j);
            sum += xs[(size_t)cj * DLAT + lane];
        }
    }
    float di = dinv[s];
    float y  = di * sum;
    size_t o = (size_t)s * DLAT + lane;
    if (is_final) {
        out[o] = (out[o] + y) * (1.0f / 3.0f);
    } else {
        out[o] += y;
        xs_next[o] = di * y;
    }
}

extern "C" void kernel_launch(void* const* d_in, const int* in_sizes, int n_in,
                              void* d_out, int out_size, void* d_ws, size_t ws_size,
                              hipStream_t stream) {
    const float* feats = (const float*)d_in[0];
    const int*   eidx  = (const int*)d_in[1];
    const float* pref  = (const float*)d_in[2];
    const float* W1    = (const float*)d_in[3];
    const float* b1    = (const float*)d_in[4];
    const float* W2    = (const float*)d_in[5];
    const float* b2    = (const float*)d_in[6];

    const int E = in_sizes[1] / 2;
    const int* src = eidx;
    const int* dst = eidx + E;

    char* ws = (char*)d_ws;
    size_t off = 0;
    auto alloc = [&](size_t bytes) -> void* {
        void* p = ws + off;
        off += (bytes + 255) & ~(size_t)255;
        return p;
    };
    const size_t xbytes = (size_t)NUM_NODES * DLAT * sizeof(float);
    float* xsA   = (float*)alloc(xbytes);
    float* xsB   = (float*)alloc(xbytes);
    int*   colbf = (int*)alloc((size_t)E * sizeof(int));
    int*   deg   = (int*)alloc((size_t)NUM_NODES * sizeof(int));
    float* dinv  = (float*)alloc((size_t)NUM_NODES * sizeof(float));
    int*   rowp  = (int*)alloc((size_t)(NUM_NODES + 1) * sizeof(int));
    int*   cnt   = (int*)alloc((size_t)NUM_NODES * sizeof(int));
    int*   part  = (int*)alloc(1024 * sizeof(int));
    unsigned short* w1t = (unsigned short*)alloc((size_t)FEAT_DIM * HID * 2);
    unsigned short* w2t = (unsigned short*)alloc((size_t)HID * DLAT * 2);
    float* out = (float*)d_out;

    const int nb = (NUM_NODES + 255) / 256;  // 586 blocks <= 1024

    // degrees + normalization
    hipMemsetAsync(deg, 0, (size_t)NUM_NODES * sizeof(int), stream);
    hipMemsetAsync(cnt, 0, (size_t)NUM_NODES * sizeof(int), stream);
    deg_kernel<<<(E + 255) / 256, 256, 0, stream>>>(src, deg, E);
    dinv_kernel<<<nb, 256, 0, stream>>>(deg, dinv, NUM_NODES);

    // rowptr = exclusive scan of deg
    scan_partial<<<nb, 256, 0, stream>>>(deg, part, NUM_NODES);
    scan_offsets<<<1, 1024, 0, stream>>>(part, nb);
    scan_rowptr<<<nb, 256, 0, stream>>>(deg, part, rowp, NUM_NODES);

    // CSR column fill
    fill_csr<<<(E + 255) / 256, 256, 0, stream>>>(src, dst, rowp, cnt, colbf, E);

    // weights -> bf16 transposed
    convert_weights<<<(FEAT_DIM * HID + HID * DLAT + 255) / 256, 256, 0, stream>>>(W1, W2, w1t, w2t);

    // x0: item MLP + preference; out = x0, xsA = dinv * x0
    mlp_kernel<<<(NUM_ITEM + 63) / 64, 256, 0, stream>>>(feats, w1t, w2t, b1, b2, dinv, out, xsA);
    pref_init<<<(NUM_USER * DLAT / 4 + 255) / 256, 256, 0, stream>>>(pref, dinv, out, xsA, NUM_USER * DLAT / 4);

    // hop 1: y1 = dinv * (A xsA); out += y1; xsB = dinv * y1
    const int hopBlocks = (NUM_NODES * 64 + 255) / 256;
    hop_csr<<<hopBlocks, 256, 0, stream>>>(rowp, colbf, dinv, xsA, out, xsB, 0, NUM_NODES);

    // hop 2: y2 = dinv * (A xsB); out = (out + y2) / 3
    hop_csr<<<hopBlocks, 256, 0, stream>>>(rowp, colbf, dinv, xsB, out, nullptr, 1, NUM_NODES);
}

// Round 3
// 1108.278 us; speedup vs baseline: 2.8020x; 1.2659x over previous
//
#include <hip/hip_runtime.h>

#define NUM_USER 100000
#define NUM_ITEM 50000
#define NUM_NODES 150000
#define FEAT_DIM 512
#define DLAT 64
#define HID 256

typedef float f32x4 __attribute__((ext_vector_type(4)));
typedef __bf16 bf16x8 __attribute__((ext_vector_type(8)));
typedef unsigned short ushort8v __attribute__((ext_vector_type(8)));

union BF8 { ushort8v u; bf16x8 b; };

__device__ inline unsigned short f2bf_rne(float f) {
    unsigned u = __float_as_uint(f);
    u += 0x7FFFu + ((u >> 16) & 1u);
    return (unsigned short)(u >> 16);
}

// ---------------- degree ----------------
__global__ void deg_kernel(const int* __restrict__ src, int* __restrict__ deg, int E) {
    int i = blockIdx.x * blockDim.x + threadIdx.x;
    if (i < E) atomicAdd(&deg[src[i]], 1);
}

__global__ void dinv_kernel(const int* __restrict__ deg, float* __restrict__ dinv, int n) {
    int i = blockIdx.x * blockDim.x + threadIdx.x;
    if (i < n) {
        int d = deg[i];
        dinv[i] = d > 0 ? rsqrtf((float)d) : 0.0f;
    }
}

// ---------------- hierarchical exclusive scan for rowptr ----------------
__global__ void scan_partial(const int* __restrict__ deg, int* __restrict__ partial, int n) {
    __shared__ int sdata[256];
    int t = threadIdx.x;
    int i = blockIdx.x * 256 + t;
    sdata[t] = (i < n) ? deg[i] : 0;
    __syncthreads();
    for (int s = 128; s > 0; s >>= 1) {
        if (t < s) sdata[t] += sdata[t + s];
        __syncthreads();
    }
    if (t == 0) partial[blockIdx.x] = sdata[0];
}

__global__ void scan_offsets(int* __restrict__ partial, int nb) {
    __shared__ int s[1024];
    int t = threadIdx.x;
    s[t] = (t < nb) ? partial[t] : 0;
    __syncthreads();
    for (int off = 1; off < 1024; off <<= 1) {
        int add = (t >= off) ? s[t - off] : 0;
        __syncthreads();
        s[t] += add;
        __syncthreads();
    }
    if (t < nb) partial[t] = (t == 0) ? 0 : s[t - 1];  // exclusive
}

__global__ void scan_rowptr(const int* __restrict__ deg, const int* __restrict__ blockoff,
                            int* __restrict__ rowptr, int n) {
    __shared__ int s[256];
    int t = threadIdx.x;
    int i = blockIdx.x * 256 + t;
    int v = (i < n) ? deg[i] : 0;
    s[t] = v;
    __syncthreads();
    for (int off = 1; off < 256; off <<= 1) {
        int add = (t >= off) ? s[t - off] : 0;
        __syncthreads();
        s[t] += add;
        __syncthreads();
    }
    int incl = s[t];
    int base = blockoff[blockIdx.x];
    if (i < n) {
        rowptr[i] = base + incl - v;
        if (i == n - 1) rowptr[n] = base + incl;
    }
}

// ---------------- CSR fill ----------------
__global__ void fill_csr(const int* __restrict__ src, const int* __restrict__ dst,
                         const int* __restrict__ rowptr, int* __restrict__ cnt,
                         int* __restrict__ col, int E) {
    int i = blockIdx.x * blockDim.x + threadIdx.x;
    if (i < E) {
        int s = src[i];
        int pos = atomicAdd(&cnt[s], 1);
        col[rowptr[s] + pos] = dst[i];
    }
}

// ---------------- weight conversion (transpose to bf16) ----------------
__global__ void convert_weights(const float* __restrict__ W1, const float* __restrict__ W2,
                                unsigned short* __restrict__ w1t, unsigned short* __restrict__ w2t) {
    int idx = blockIdx.x * blockDim.x + threadIdx.x;
    if (idx < FEAT_DIM * HID) {
        int k = idx / HID, n = idx % HID;
        w1t[(size_t)n * FEAT_DIM + k] = f2bf_rne(W1[idx]);
    } else {
        int j = idx - FEAT_DIM * HID;
        if (j < HID * DLAT) {
            int k = j / DLAT, n = j % DLAT;
            w2t[(size_t)n * HID + k] = f2bf_rne(W2[j]);
        }
    }
}

// ---------------- fused item MLP: bf16 MFMA ----------------
__launch_bounds__(256)
__global__ void mlp_kernel(const float* __restrict__ feats,
                           const unsigned short* __restrict__ w1t,
                           const unsigned short* __restrict__ w2t,
                           const float* __restrict__ b1,
                           const float* __restrict__ b2,
                           const float* __restrict__ dinv,
                           float* __restrict__ out,
                           unsigned short* __restrict__ xs) {
    __shared__ unsigned short sH[64][264];

    const int tid  = threadIdx.x;
    const int lane = tid & 63;
    const int w    = tid >> 6;
    const int wr   = w >> 1;
    const int wc   = w & 1;
    const int l15  = lane & 15;
    const int l4   = lane >> 4;
    const int item0 = blockIdx.x * 64;

    f32x4 acc[2][8];
    #pragma unroll
    for (int i = 0; i < 2; ++i)
        #pragma unroll
        for (int j = 0; j < 8; ++j) acc[i][j] = (f32x4)0.0f;

    for (int kk = 0; kk < 16; ++kk) {
        const int kbase = kk * 32 + l4 * 8;
        bf16x8 afrag[2];
        #pragma unroll
        for (int rf = 0; rf < 2; ++rf) {
            int row = item0 + wr * 32 + rf * 16 + l15;
            row = min(row, NUM_ITEM - 1);
            const float4* ap = reinterpret_cast<const float4*>(feats + (size_t)row * FEAT_DIM + kbase);
            float4 x0 = ap[0], x1 = ap[1];
            BF8 t;
            t.u[0] = f2bf_rne(x0.x); t.u[1] = f2bf_rne(x0.y);
            t.u[2] = f2bf_rne(x0.z); t.u[3] = f2bf_rne(x0.w);
            t.u[4] = f2bf_rne(x1.x); t.u[5] = f2bf_rne(x1.y);
            t.u[6] = f2bf_rne(x1.z); t.u[7] = f2bf_rne(x1.w);
            afrag[rf] = t.b;
        }
        #pragma unroll
        for (int cf = 0; cf < 8; ++cf) {
            int colc = wc * 128 + cf * 16 + l15;
            BF8 t;
            t.u = *reinterpret_cast<const ushort8v*>(w1t + (size_t)colc * FEAT_DIM + kbase);
            acc[0][cf] = __builtin_amdgcn_mfma_f32_16x16x32_bf16(afrag[0], t.b, acc[0][cf], 0, 0, 0);
            acc[1][cf] = __builtin_amdgcn_mfma_f32_16x16x32_bf16(afrag[1], t.b, acc[1][cf], 0, 0, 0);
        }
    }

    #pragma unroll
    for (int rf = 0; rf < 2; ++rf) {
        #pragma unroll
        for (int cf = 0; cf < 8; ++cf) {
            int colc = wc * 128 + cf * 16 + l15;
            float bias = b1[colc];
            #pragma unroll
            for (int r = 0; r < 4; ++r) {
                int lrow = wr * 32 + rf * 16 + l4 * 4 + r;
                float h = acc[rf][cf][r] + bias;
                h = h > 0.0f ? h : 0.01f * h;
                sH[lrow][colc] = f2bf_rne(h);
            }
        }
    }
    __syncthreads();

    f32x4 acc2[4];
    #pragma unroll
    for (int j = 0; j < 4; ++j) acc2[j] = (f32x4)0.0f;

    for (int kk = 0; kk < 8; ++kk) {
        const int kbase = kk * 32 + l4 * 8;
        BF8 ta;
        ta.u = *reinterpret_cast<const ushort8v*>(&sH[w * 16 + l15][kbase]);
        #pragma unroll
        for (int cf = 0; cf < 4; ++cf) {
            int colc = cf * 16 + l15;
            BF8 tb;
            tb.u = *reinterpret_cast<const ushort8v*>(w2t + (size_t)colc * HID + kbase);
            acc2[cf] = __builtin_amdgcn_mfma_f32_16x16x32_bf16(ta.b, tb.b, acc2[cf], 0, 0, 0);
        }
    }

    #pragma unroll
    for (int cf = 0; cf < 4; ++cf) {
        int colc = cf * 16 + l15;
        float bias = b2[colc];
        #pragma unroll
        for (int r = 0; r < 4; ++r) {
            int item = item0 + w * 16 + l4 * 4 + r;
            if (item < NUM_ITEM) {
                int node = NUM_USER + item;
                float v = acc2[cf][r] + bias;
                out[(size_t)node * DLAT + colc] = v;
                xs [(size_t)node * DLAT + colc] = f2bf_rne(v * dinv[node]);
            }
        }
    }
}

// ---------------- user init: out = pref, xs = bf16(pref * dinv) ----------------
__global__ void pref_init(const float* __restrict__ pref, const float* __restrict__ dinv,
                          float* __restrict__ out, unsigned short* __restrict__ xs, int n4) {
    int i = blockIdx.x * blockDim.x + threadIdx.x;  // float4 index over NUM_USER*64/4
    if (i < n4) {
        float4 v = reinterpret_cast<const float4*>(pref)[i];
        float di = dinv[i >> 4];
        reinterpret_cast<float4*>(out)[i] = v;
        uint2 p;
        p.x = (unsigned)f2bf_rne(v.x * di) | ((unsigned)f2bf_rne(v.y * di) << 16);
        p.y = (unsigned)f2bf_rne(v.z * di) | ((unsigned)f2bf_rne(v.w * di) << 16);
        *reinterpret_cast<uint2*>(xs + (size_t)i * 4) = p;
    }
}

// ---------------- CSR gather hop (bf16 state): one wave per node ----------------
// lane = (h, r): h = lane>>5 picks neighbor parity, r = lane&31 handles dims 2r, 2r+1.
// Each half-wave reads one 128B bf16 row per iteration (2 rows/wave/iter).
__launch_bounds__(256)
__global__ void hop_csr(const int* __restrict__ rowptr, const int* __restrict__ col,
                        const float* __restrict__ dinv, const unsigned short* __restrict__ xs,
                        float* __restrict__ out, unsigned short* __restrict__ xs_next,
                        int is_final, int n) {
    const int wave = (blockIdx.x * blockDim.x + threadIdx.x) >> 6;
    const int lane = threadIdx.x & 63;
    if (wave >= n) return;
    const int r0 = rowptr[wave];
    const int r1 = rowptr[wave + 1];
    const int h  = lane >> 5;
    const int r  = lane & 31;

    float s0 = 0.0f, s1 = 0.0f;
    for (int base = r0; base < r1; base += 64) {
        int rem = r1 - base;
        int m = rem < 64 ? rem : 64;
        int cvec = (lane < rem) ? col[base + lane] : 0;
        int j = 0;
        for (; j + 1 < m; j += 2) {
            int cj = __shfl(cvec, j + h);
            unsigned v = *reinterpret_cast<const unsigned*>(xs + (size_t)cj * DLAT + 2 * r);
            s0 += __uint_as_float(v << 16);
            s1 += __uint_as_float(v & 0xffff0000u);
        }
        if (j < m) {  // odd tail: half 0 only
            int cj = __shfl(cvec, j);
            if (h == 0) {
                unsigned v = *reinterpret_cast<const unsigned*>(xs + (size_t)cj * DLAT + 2 * r);
                s0 += __uint_as_float(v << 16);
                s1 += __uint_as_float(v & 0xffff0000u);
            }
        }
    }
    s0 += __shfl_xor(s0, 32);
    s1 += __shfl_xor(s1, 32);

    if (h == 0) {
        float di = dinv[wave];
        float y0 = di * s0;
        float y1 = di * s1;
        size_t o = (size_t)wave * DLAT + 2 * r;
        float2 prev = *reinterpret_cast<const float2*>(out + o);
        if (is_final) {
            float2 wv;
            wv.x = (prev.x + y0) * (1.0f / 3.0f);
            wv.y = (prev.y + y1) * (1.0f / 3.0f);
            *reinterpret_cast<float2*>(out + o) = wv;
        } else {
            float2 wv;
            wv.x = prev.x + y0;
            wv.y = prev.y + y1;
            *reinterpret_cast<float2*>(out + o) = wv;
            unsigned p = (unsigned)f2bf_rne(di * y0) | ((unsigned)f2bf_rne(di * y1) << 16);
            *reinterpret_cast<unsigned*>(xs_next + o) = p;
        }
    }
}

extern "C" void kernel_launch(void* const* d_in, const int* in_sizes, int n_in,
                              void* d_out, int out_size, void* d_ws, size_t ws_size,
                              hipStream_t stream) {
    const float* feats = (const float*)d_in[0];
    const int*   eidx  = (const int*)d_in[1];
    const float* pref  = (const float*)d_in[2];
    const float* W1    = (const float*)d_in[3];
    const float* b1    = (const float*)d_in[4];
    const float* W2    = (const float*)d_in[5];
    const float* b2    = (const float*)d_in[6];

    const int E = in_sizes[1] / 2;
    const int* src = eidx;
    const int* dst = eidx + E;

    char* ws = (char*)d_ws;
    size_t off = 0;
    auto alloc = [&](size_t bytes) -> void* {
        void* p = ws + off;
        off += (bytes + 255) & ~(size_t)255;
        return p;
    };
    const size_t xsbytes = (size_t)NUM_NODES * DLAT * sizeof(unsigned short);
    unsigned short* xsA = (unsigned short*)alloc(xsbytes);
    unsigned short* xsB = (unsigned short*)alloc(xsbytes);
    int*   colbf = (int*)alloc((size_t)E * sizeof(int));
    int*   deg   = (int*)alloc((size_t)NUM_NODES * sizeof(int));
    float* dinv  = (float*)alloc((size_t)NUM_NODES * sizeof(float));
    int*   rowp  = (int*)alloc((size_t)(NUM_NODES + 1) * sizeof(int));
    int*   cnt   = (int*)alloc((size_t)NUM_NODES * sizeof(int));
    int*   part  = (int*)alloc(1024 * sizeof(int));
    unsigned short* w1t = (unsigned short*)alloc((size_t)FEAT_DIM * HID * 2);
    unsigned short* w2t = (unsigned short*)alloc((size_t)HID * DLAT * 2);
    float* out = (float*)d_out;

    const int nb = (NUM_NODES + 255) / 256;  // 586 blocks <= 1024

    // degrees + normalization
    hipMemsetAsync(deg, 0, (size_t)NUM_NODES * sizeof(int), stream);
    hipMemsetAsync(cnt, 0, (size_t)NUM_NODES * sizeof(int), stream);
    deg_kernel<<<(E + 255) / 256, 256, 0, stream>>>(src, deg, E);
    dinv_kernel<<<nb, 256, 0, stream>>>(deg, dinv, NUM_NODES);

    // rowptr = exclusive scan of deg
    scan_partial<<<nb, 256, 0, stream>>>(deg, part, NUM_NODES);
    scan_offsets<<<1, 1024, 0, stream>>>(part, nb);
    scan_rowptr<<<nb, 256, 0, stream>>>(deg, part, rowp, NUM_NODES);

    // CSR column fill
    fill_csr<<<(E + 255) / 256, 256, 0, stream>>>(src, dst, rowp, cnt, colbf, E);

    // weights -> bf16 transposed
    convert_weights<<<(FEAT_DIM * HID + HID * DLAT + 255) / 256, 256, 0, stream>>>(W1, W2, w1t, w2t);

    // x0: item MLP + preference; out = x0, xsA = bf16(dinv * x0)
    mlp_kernel<<<(NUM_ITEM + 63) / 64, 256, 0, stream>>>(feats, w1t, w2t, b1, b2, dinv, out, xsA);
    pref_init<<<(NUM_USER * DLAT / 4 + 255) / 256, 256, 0, stream>>>(pref, dinv, out, xsA, NUM_USER * DLAT / 4);

    // hop 1: y1 = dinv * (A xsA); out += y1; xsB = bf16(dinv * y1)
    const int hopBlocks = (NUM_NODES * 64 + 255) / 256;
    hop_csr<<<hopBlocks, 256, 0, stream>>>(rowp, colbf, dinv, xsA, out, xsB, 0, NUM_NODES);

    // hop 2: y2 = dinv * (A xsB); out = (out + y2) / 3
    hop_csr<<<hopBlocks, 256, 0, stream>>>(rowp, colbf, dinv, xsB, out, nullptr, 1, NUM_NODES);
}

// Round 4
// 745.586 us; speedup vs baseline: 4.1650x; 1.4865x over previous
//
#include <hip/hip_runtime.h>

#define NUM_USER 100000
#define NUM_ITEM 50000
#define NUM_NODES 150000
#define FEAT_DIM 512
#define DLAT 64
#define HID 256

// bucketed CSR build
#define BSHIFT 9
#define BWIDTH 512                       // nodes per bucket
#define NBUCK 293                        // ceil(150000/512)
#define CHUNK 4096                       // edges per bucket_scatter block

typedef float f32x4 __attribute__((ext_vector_type(4)));
typedef __bf16 bf16x8 __attribute__((ext_vector_type(8)));
typedef unsigned short ushort8v __attribute__((ext_vector_type(8)));

union BF8 { ushort8v u; bf16x8 b; };

__device__ inline unsigned short f2bf_rne(float f) {
    unsigned u = __float_as_uint(f);
    u += 0x7FFFu + ((u >> 16) & 1u);
    return (unsigned short)(u >> 16);
}

// ---------------- pass A: bucket histogram ----------------
__global__ void bucket_hist(const int* __restrict__ src, int* __restrict__ bhist, int E) {
    __shared__ int h[NBUCK];
    for (int i = threadIdx.x; i < NBUCK; i += blockDim.x) h[i] = 0;
    __syncthreads();
    const int stride = gridDim.x * blockDim.x;
    for (int i = blockIdx.x * blockDim.x + threadIdx.x; i < E; i += stride)
        atomicAdd(&h[src[i] >> BSHIFT], 1);
    __syncthreads();
    for (int i = threadIdx.x; i < NBUCK; i += blockDim.x)
        if (h[i]) atomicAdd(&bhist[i], h[i]);
}

// ---------------- pass A2: exclusive scan of bucket histogram ----------------
__global__ void bucket_scan(const int* __restrict__ bhist, int* __restrict__ bbase) {
    __shared__ int s[512];
    const int t = threadIdx.x;
    const int v = (t < NBUCK) ? bhist[t] : 0;
    s[t] = v;
    __syncthreads();
    for (int off = 1; off < 512; off <<= 1) {
        int add = (t >= off) ? s[t - off] : 0;
        __syncthreads();
        s[t] += add;
        __syncthreads();
    }
    if (t < NBUCK) bbase[t] = s[t] - v;  // exclusive
}

// ---------------- pass B: scatter edges into bucket-grouped packed pairs ----------------
// pair = (s & 511) << 18 | d   (d < 2^18)
__global__ void bucket_scatter(const int* __restrict__ src, const int* __restrict__ dst,
                               const int* __restrict__ bbase, int* __restrict__ gfill,
                               unsigned* __restrict__ pairs, int E) {
    __shared__ int h[NBUCK];
    __shared__ int base[NBUCK];
    const int t = threadIdx.x;
    for (int i = t; i < NBUCK; i += blockDim.x) h[i] = 0;
    __syncthreads();
    const int i0 = blockIdx.x * CHUNK;
    const int i1 = min(i0 + CHUNK, E);
    for (int i = i0 + t; i < i1; i += blockDim.x)
        atomicAdd(&h[src[i] >> BSHIFT], 1);
    __syncthreads();
    for (int i = t; i < NBUCK; i += blockDim.x) {
        int c = h[i];
        base[i] = c ? (bbase[i] + atomicAdd(&gfill[i], c)) : 0;
        h[i] = 0;
    }
    __syncthreads();
    for (int i = i0 + t; i < i1; i += blockDim.x) {
        int s = src[i], d = dst[i];
        int b = s >> BSHIFT;
        int pos = atomicAdd(&h[b], 1);
        pairs[base[b] + pos] = ((unsigned)(s & (BWIDTH - 1)) << 18) | (unsigned)d;
    }
}

// ---------------- pass CD: per-bucket degree count + rowptr/dinv + CSR fill ----------------
__launch_bounds__(256)
__global__ void csr_build(const int* __restrict__ bhist, const int* __restrict__ bbase,
                          const unsigned* __restrict__ pairs,
                          int* __restrict__ rowptr, float* __restrict__ dinv,
                          int* __restrict__ col) {
    __shared__ int degl[BWIDTH];
    __shared__ int offl[BWIDTH];
    const int b = blockIdx.x;
    const int t = threadIdx.x;
    const int node0 = b << BSHIFT;
    const int e0 = bbase[b];
    const int ecnt = bhist[b];

    degl[t] = 0; degl[t + 256] = 0;
    __syncthreads();
    for (int i = t; i < ecnt; i += 256)
        atomicAdd(&degl[pairs[e0 + i] >> 18], 1);
    __syncthreads();

    // inclusive scan of degl[0..511] (2 elements per thread)
    const int v0 = degl[t], v1 = degl[t + 256];
    offl[t] = v0; offl[t + 256] = v1;
    __syncthreads();
    for (int off = 1; off < 512; off <<= 1) {
        int a0 = (t >= off) ? offl[t - off] : 0;
        int a1 = offl[t + 256 - off];
        __syncthreads();
        offl[t] += a0;
        offl[t + 256] += a1;
        __syncthreads();
    }
    const int excl0 = offl[t] - v0;
    const int excl1 = offl[t + 256] - v1;

    const int n0 = node0 + t, n1 = node0 + t + 256;
    if (n0 < NUM_NODES) {
        rowptr[n0] = e0 + excl0;
        dinv[n0] = v0 > 0 ? rsqrtf((float)v0) : 0.0f;
    }
    if (n1 < NUM_NODES) {
        rowptr[n1] = e0 + excl1;
        dinv[n1] = v1 > 0 ? rsqrtf((float)v1) : 0.0f;
    }
    if (b == NBUCK - 1 && t == 0) rowptr[NUM_NODES] = e0 + ecnt;
    __syncthreads();

    // reuse: offl <- exclusive base, degl <- fill counters
    offl[t] = excl0; offl[t + 256] = excl1;
    degl[t] = 0;     degl[t + 256] = 0;
    __syncthreads();
    for (int i = t; i < ecnt; i += 256) {
        unsigned p = pairs[e0 + i];
        int sl = p >> 18;
        int d  = (int)(p & 0x3FFFFu);
        int pos = atomicAdd(&degl[sl], 1);
        col[e0 + offl[sl] + pos] = d;
    }
}

// ---------------- weight conversion (transpose to bf16) ----------------
__global__ void convert_weights(const float* __restrict__ W1, const float* __restrict__ W2,
                                unsigned short* __restrict__ w1t, unsigned short* __restrict__ w2t) {
    int idx = blockIdx.x * blockDim.x + threadIdx.x;
    if (idx < FEAT_DIM * HID) {
        int k = idx / HID, n = idx % HID;
        w1t[(size_t)n * FEAT_DIM + k] = f2bf_rne(W1[idx]);
    } else {
        int j = idx - FEAT_DIM * HID;
        if (j < HID * DLAT) {
            int k = j / DLAT, n = j % DLAT;
            w2t[(size_t)n * HID + k] = f2bf_rne(W2[j]);
        }
    }
}

// ---------------- fused item MLP: bf16 MFMA ----------------
__launch_bounds__(256)
__global__ void mlp_kernel(const float* __restrict__ feats,
                           const unsigned short* __restrict__ w1t,
                           const unsigned short* __restrict__ w2t,
                           const float* __restrict__ b1,
                           const float* __restrict__ b2,
                           const float* __restrict__ dinv,
                           float* __restrict__ out,
                           unsigned short* __restrict__ xs) {
    __shared__ unsigned short sH[64][264];

    const int tid  = threadIdx.x;
    const int lane = tid & 63;
    const int w    = tid >> 6;
    const int wr   = w >> 1;
    const int wc   = w & 1;
    const int l15  = lane & 15;
    const int l4   = lane >> 4;
    const int item0 = blockIdx.x * 64;

    f32x4 acc[2][8];
    #pragma unroll
    for (int i = 0; i < 2; ++i)
        #pragma unroll
        for (int j = 0; j < 8; ++j) acc[i][j] = (f32x4)0.0f;

    for (int kk = 0; kk < 16; ++kk) {
        const int kbase = kk * 32 + l4 * 8;
        bf16x8 afrag[2];
        #pragma unroll
        for (int rf = 0; rf < 2; ++rf) {
            int row = item0 + wr * 32 + rf * 16 + l15;
            row = min(row, NUM_ITEM - 1);
            const float4* ap = reinterpret_cast<const float4*>(feats + (size_t)row * FEAT_DIM + kbase);
            float4 x0 = ap[0], x1 = ap[1];
            BF8 t;
            t.u[0] = f2bf_rne(x0.x); t.u[1] = f2bf_rne(x0.y);
            t.u[2] = f2bf_rne(x0.z); t.u[3] = f2bf_rne(x0.w);
            t.u[4] = f2bf_rne(x1.x); t.u[5] = f2bf_rne(x1.y);
            t.u[6] = f2bf_rne(x1.z); t.u[7] = f2bf_rne(x1.w);
            afrag[rf] = t.b;
        }
        #pragma unroll
        for (int cf = 0; cf < 8; ++cf) {
            int colc = wc * 128 + cf * 16 + l15;
            BF8 t;
            t.u = *reinterpret_cast<const ushort8v*>(w1t + (size_t)colc * FEAT_DIM + kbase);
            acc[0][cf] = __builtin_amdgcn_mfma_f32_16x16x32_bf16(afrag[0], t.b, acc[0][cf], 0, 0, 0);
            acc[1][cf] = __builtin_amdgcn_mfma_f32_16x16x32_bf16(afrag[1], t.b, acc[1][cf], 0, 0, 0);
        }
    }

    #pragma unroll
    for (int rf = 0; rf < 2; ++rf) {
        #pragma unroll
        for (int cf = 0; cf < 8; ++cf) {
            int colc = wc * 128 + cf * 16 + l15;
            float bias = b1[colc];
            #pragma unroll
            for (int r = 0; r < 4; ++r) {
                int lrow = wr * 32 + rf * 16 + l4 * 4 + r;
                float h = acc[rf][cf][r] + bias;
                h = h > 0.0f ? h : 0.01f * h;
                sH[lrow][colc] = f2bf_rne(h);
            }
        }
    }
    __syncthreads();

    f32x4 acc2[4];
    #pragma unroll
    for (int j = 0; j < 4; ++j) acc2[j] = (f32x4)0.0f;

    for (int kk = 0; kk < 8; ++kk) {
        const int kbase = kk * 32 + l4 * 8;
        BF8 ta;
        ta.u = *reinterpret_cast<const ushort8v*>(&sH[w * 16 + l15][kbase]);
        #pragma unroll
        for (int cf = 0; cf < 4; ++cf) {
            int colc = cf * 16 + l15;
            BF8 tb;
            tb.u = *reinterpret_cast<const ushort8v*>(w2t + (size_t)colc * HID + kbase);
            acc2[cf] = __builtin_amdgcn_mfma_f32_16x16x32_bf16(ta.b, tb.b, acc2[cf], 0, 0, 0);
        }
    }

    #pragma unroll
    for (int cf = 0; cf < 4; ++cf) {
        int colc = cf * 16 + l15;
        float bias = b2[colc];
        #pragma unroll
        for (int r = 0; r < 4; ++r) {
            int item = item0 + w * 16 + l4 * 4 + r;
            if (item < NUM_ITEM) {
                int node = NUM_USER + item;
                float v = acc2[cf][r] + bias;
                out[(size_t)node * DLAT + colc] = v;
                xs [(size_t)node * DLAT + colc] = f2bf_rne(v * dinv[node]);
            }
        }
    }
}

// ---------------- user init: out = pref, xs = bf16(pref * dinv) ----------------
__global__ void pref_init(const float* __restrict__ pref, const float* __restrict__ dinv,
                          float* __restrict__ out, unsigned short* __restrict__ xs, int n4) {
    int i = blockIdx.x * blockDim.x + threadIdx.x;  // float4 index over NUM_USER*64/4
    if (i < n4) {
        float4 v = reinterpret_cast<const float4*>(pref)[i];
        float di = dinv[i >> 4];
        reinterpret_cast<float4*>(out)[i] = v;
        uint2 p;
        p.x = (unsigned)f2bf_rne(v.x * di) | ((unsigned)f2bf_rne(v.y * di) << 16);
        p.y = (unsigned)f2bf_rne(v.z * di) | ((unsigned)f2bf_rne(v.w * di) << 16);
        *reinterpret_cast<uint2*>(xs + (size_t)i * 4) = p;
    }
}

// ---------------- CSR gather hop (bf16 state): one wave per node ----------------
__launch_bounds__(256)
__global__ void hop_csr(const int* __restrict__ rowptr, const int* __restrict__ col,
                        const float* __restrict__ dinv, const unsigned short* __restrict__ xs,
                        float* __restrict__ out, unsigned short* __restrict__ xs_next,
                        int is_final, int n) {
    const int wave = (blockIdx.x * blockDim.x + threadIdx.x) >> 6;
    const int lane = threadIdx.x & 63;
    if (wave >= n) return;
    const int r0 = rowptr[wave];
    const int r1 = rowptr[wave + 1];
    const int h  = lane >> 5;
    const int r  = lane & 31;

    float s0 = 0.0f, s1 = 0.0f;
    for (int base = r0; base < r1; base += 64) {
        int rem = r1 - base;
        int m = rem < 64 ? rem : 64;
        int cvec = (lane < rem) ? col[base + lane] : 0;
        int j = 0;
        for (; j + 1 < m; j += 2) {
            int cj = __shfl(cvec, j + h);
            unsigned v = *reinterpret_cast<const unsigned*>(xs + (size_t)cj * DLAT + 2 * r);
            s0 += __uint_as_float(v << 16);
            s1 += __uint_as_float(v & 0xffff0000u);
        }
        if (j < m) {  // odd tail: half 0 only
            int cj = __shfl(cvec, j);
            if (h == 0) {
                unsigned v = *reinterpret_cast<const unsigned*>(xs + (size_t)cj * DLAT + 2 * r);
                s0 += __uint_as_float(v << 16);
                s1 += __uint_as_float(v & 0xffff0000u);
            }
        }
    }
    s0 += __shfl_xor(s0, 32);
    s1 += __shfl_xor(s1, 32);

    if (h == 0) {
        float di = dinv[wave];
        float y0 = di * s0;
        float y1 = di * s1;
        size_t o = (size_t)wave * DLAT + 2 * r;
        float2 prev = *reinterpret_cast<const float2*>(out + o);
        if (is_final) {
            float2 wv;
            wv.x = (prev.x + y0) * (1.0f / 3.0f);
            wv.y = (prev.y + y1) * (1.0f / 3.0f);
            *reinterpret_cast<float2*>(out + o) = wv;
        } else {
            float2 wv;
            wv.x = prev.x + y0;
            wv.y = prev.y + y1;
            *reinterpret_cast<float2*>(out + o) = wv;
            unsigned p = (unsigned)f2bf_rne(di * y0) | ((unsigned)f2bf_rne(di * y1) << 16);
            *reinterpret_cast<unsigned*>(xs_next + o) = p;
        }
    }
}

extern "C" void kernel_launch(void* const* d_in, const int* in_sizes, int n_in,
                              void* d_out, int out_size, void* d_ws, size_t ws_size,
                              hipStream_t stream) {
    const float* feats = (const float*)d_in[0];
    const int*   eidx  = (const int*)d_in[1];
    const float* pref  = (const float*)d_in[2];
    const float* W1    = (const float*)d_in[3];
    const float* b1    = (const float*)d_in[4];
    const float* W2    = (const float*)d_in[5];
    const float* b2    = (const float*)d_in[6];

    const int E = in_sizes[1] / 2;
    const int* src = eidx;
    const int* dst = eidx + E;

    char* ws = (char*)d_ws;
    size_t off = 0;
    auto alloc = [&](size_t bytes) -> void* {
        void* p = ws + off;
        off += (bytes + 255) & ~(size_t)255;
        return p;
    };
    const size_t xsbytes = (size_t)NUM_NODES * DLAT * sizeof(unsigned short);
    unsigned short* xsA = (unsigned short*)alloc(xsbytes);
    unsigned short* xsB = (unsigned short*)alloc(xsbytes);
    int*      colbf = (int*)alloc((size_t)E * sizeof(int));
    unsigned* pairs = (unsigned*)alloc((size_t)E * sizeof(unsigned));
    float*    dinv  = (float*)alloc((size_t)NUM_NODES * sizeof(float));
    int*      rowp  = (int*)alloc((size_t)(NUM_NODES + 1) * sizeof(int));
    int*      bhist = (int*)alloc((size_t)NBUCK * sizeof(int));
    int*      bbase = (int*)alloc((size_t)NBUCK * sizeof(int));
    int*      gfill = (int*)alloc((size_t)NBUCK * sizeof(int));
    unsigned short* w1t = (unsigned short*)alloc((size_t)FEAT_DIM * HID * 2);
    unsigned short* w2t = (unsigned short*)alloc((size_t)HID * DLAT * 2);
    float* out = (float*)d_out;

    // bucketed CSR build
    hipMemsetAsync(bhist, 0, (size_t)NBUCK * sizeof(int), stream);
    hipMemsetAsync(gfill, 0, (size_t)NBUCK * sizeof(int), stream);
    bucket_hist<<<512, 256, 0, stream>>>(src, bhist, E);
    bucket_scan<<<1, 512, 0, stream>>>(bhist, bbase);
    bucket_scatter<<<(E + CHUNK - 1) / CHUNK, 256, 0, stream>>>(src, dst, bbase, gfill, pairs, E);
    csr_build<<<NBUCK, 256, 0, stream>>>(bhist, bbase, pairs, rowp, dinv, colbf);

    // weights -> bf16 transposed
    convert_weights<<<(FEAT_DIM * HID + HID * DLAT + 255) / 256, 256, 0, stream>>>(W1, W2, w1t, w2t);

    // x0: item MLP + preference; out = x0, xsA = bf16(dinv * x0)
    mlp_kernel<<<(NUM_ITEM + 63) / 64, 256, 0, stream>>>(feats, w1t, w2t, b1, b2, dinv, out, xsA);
    pref_init<<<(NUM_USER * DLAT / 4 + 255) / 256, 256, 0, stream>>>(pref, dinv, out, xsA, NUM_USER * DLAT / 4);

    // hop 1: y1 = dinv * (A xsA); out += y1; xsB = bf16(dinv * y1)
    const int hopBlocks = (NUM_NODES * 64 + 255) / 256;
    hop_csr<<<hopBlocks, 256, 0, stream>>>(rowp, colbf, dinv, xsA, out, xsB, 0, NUM_NODES);

    // hop 2: y2 = dinv * (A xsB); out = (out + y2) / 3
    hop_csr<<<hopBlocks, 256, 0, stream>>>(rowp, colbf, dinv, xsB, out, nullptr, 1, NUM_NODES);
}

// Round 5
// 552.294 us; speedup vs baseline: 5.6226x; 1.3500x over previous
//
#include <hip/hip_runtime.h>

#define NUM_USER 100000
#define NUM_ITEM 50000
#define NUM_NODES 150000
#define FEAT_DIM 512
#define DLAT 64
#define HID 256

// bucketed CSR build
#define BSHIFT 9
#define BWIDTH 512                       // nodes per bucket
#define NBUCK 293                        // ceil(150000/512)
#define CHUNK 4096                       // edges per bucket_scatter block

typedef float f32x4 __attribute__((ext_vector_type(4)));
typedef __bf16 bf16x8 __attribute__((ext_vector_type(8)));
typedef unsigned short ushort8v __attribute__((ext_vector_type(8)));

union BF8 { ushort8v u; bf16x8 b; };

__device__ inline unsigned short f2bf_rne(float f) {
    unsigned u = __float_as_uint(f);
    u += 0x7FFFu + ((u >> 16) & 1u);
    return (unsigned short)(u >> 16);
}

__device__ inline float bf_lo(unsigned v) { return __uint_as_float(v << 16); }
__device__ inline float bf_hi(unsigned v) { return __uint_as_float(v & 0xffff0000u); }

// ---------------- pass A: bucket histogram ----------------
__global__ void bucket_hist(const int* __restrict__ src, int* __restrict__ bhist, int E) {
    __shared__ int h[NBUCK];
    for (int i = threadIdx.x; i < NBUCK; i += blockDim.x) h[i] = 0;
    __syncthreads();
    const int stride = gridDim.x * blockDim.x;
    for (int i = blockIdx.x * blockDim.x + threadIdx.x; i < E; i += stride)
        atomicAdd(&h[src[i] >> BSHIFT], 1);
    __syncthreads();
    for (int i = threadIdx.x; i < NBUCK; i += blockDim.x)
        if (h[i]) atomicAdd(&bhist[i], h[i]);
}

// ---------------- pass A2: exclusive scan of bucket histogram ----------------
__global__ void bucket_scan(const int* __restrict__ bhist, int* __restrict__ bbase) {
    __shared__ int s[512];
    const int t = threadIdx.x;
    const int v = (t < NBUCK) ? bhist[t] : 0;
    s[t] = v;
    __syncthreads();
    for (int off = 1; off < 512; off <<= 1) {
        int add = (t >= off) ? s[t - off] : 0;
        __syncthreads();
        s[t] += add;
        __syncthreads();
    }
    if (t < NBUCK) bbase[t] = s[t] - v;  // exclusive
}

// ---------------- pass B: scatter edges into bucket-grouped packed pairs ----------------
// pair = (s & 511) << 18 | d   (d < 2^18)
__global__ void bucket_scatter(const int* __restrict__ src, const int* __restrict__ dst,
                               const int* __restrict__ bbase, int* __restrict__ gfill,
                               unsigned* __restrict__ pairs, int E) {
    __shared__ int h[NBUCK];
    __shared__ int base[NBUCK];
    const int t = threadIdx.x;
    for (int i = t; i < NBUCK; i += blockDim.x) h[i] = 0;
    __syncthreads();
    const int i0 = blockIdx.x * CHUNK;
    const int i1 = min(i0 + CHUNK, E);
    for (int i = i0 + t; i < i1; i += blockDim.x)
        atomicAdd(&h[src[i] >> BSHIFT], 1);
    __syncthreads();
    for (int i = t; i < NBUCK; i += blockDim.x) {
        int c = h[i];
        base[i] = c ? (bbase[i] + atomicAdd(&gfill[i], c)) : 0;
        h[i] = 0;
    }
    __syncthreads();
    for (int i = i0 + t; i < i1; i += blockDim.x) {
        int s = src[i], d = dst[i];
        int b = s >> BSHIFT;
        int pos = atomicAdd(&h[b], 1);
        pairs[base[b] + pos] = ((unsigned)(s & (BWIDTH - 1)) << 18) | (unsigned)d;
    }
}

// ---------------- pass CD: per-bucket degree count + rowptr/dinv + CSR fill ----------------
__launch_bounds__(256)
__global__ void csr_build(const int* __restrict__ bhist, const int* __restrict__ bbase,
                          const unsigned* __restrict__ pairs,
                          int* __restrict__ rowptr, float* __restrict__ dinv,
                          int* __restrict__ col) {
    __shared__ int degl[BWIDTH];
    __shared__ int offl[BWIDTH];
    const int b = blockIdx.x;
    const int t = threadIdx.x;
    const int node0 = b << BSHIFT;
    const int e0 = bbase[b];
    const int ecnt = bhist[b];

    degl[t] = 0; degl[t + 256] = 0;
    __syncthreads();
    for (int i = t; i < ecnt; i += 256)
        atomicAdd(&degl[pairs[e0 + i] >> 18], 1);
    __syncthreads();

    // inclusive scan of degl[0..511] (2 elements per thread)
    const int v0 = degl[t], v1 = degl[t + 256];
    offl[t] = v0; offl[t + 256] = v1;
    __syncthreads();
    for (int off = 1; off < 512; off <<= 1) {
        int a0 = (t >= off) ? offl[t - off] : 0;
        int a1 = offl[t + 256 - off];
        __syncthreads();
        offl[t] += a0;
        offl[t + 256] += a1;
        __syncthreads();
    }
    const int excl0 = offl[t] - v0;
    const int excl1 = offl[t + 256] - v1;

    const int n0 = node0 + t, n1 = node0 + t + 256;
    if (n0 < NUM_NODES) {
        rowptr[n0] = e0 + excl0;
        dinv[n0] = v0 > 0 ? rsqrtf((float)v0) : 0.0f;
    }
    if (n1 < NUM_NODES) {
        rowptr[n1] = e0 + excl1;
        dinv[n1] = v1 > 0 ? rsqrtf((float)v1) : 0.0f;
    }
    if (b == NBUCK - 1 && t == 0) rowptr[NUM_NODES] = e0 + ecnt;
    __syncthreads();

    // reuse: offl <- exclusive base, degl <- fill counters
    offl[t] = excl0; offl[t + 256] = excl1;
    degl[t] = 0;     degl[t + 256] = 0;
    __syncthreads();
    for (int i = t; i < ecnt; i += 256) {
        unsigned p = pairs[e0 + i];
        int sl = p >> 18;
        int d  = (int)(p & 0x3FFFFu);
        int pos = atomicAdd(&degl[sl], 1);
        col[e0 + offl[sl] + pos] = d;
    }
}

// ---------------- weight conversion (transpose to bf16) ----------------
__global__ void convert_weights(const float* __restrict__ W1, const float* __restrict__ W2,
                                unsigned short* __restrict__ w1t, unsigned short* __restrict__ w2t) {
    int idx = blockIdx.x * blockDim.x + threadIdx.x;
    if (idx < FEAT_DIM * HID) {
        int k = idx / HID, n = idx % HID;
        w1t[(size_t)n * FEAT_DIM + k] = f2bf_rne(W1[idx]);
    } else {
        int j = idx - FEAT_DIM * HID;
        if (j < HID * DLAT) {
            int k = j / DLAT, n = j % DLAT;
            w2t[(size_t)n * HID + k] = f2bf_rne(W2[j]);
        }
    }
}

// ---------------- fused item MLP: bf16 MFMA ----------------
__launch_bounds__(256)
__global__ void mlp_kernel(const float* __restrict__ feats,
                           const unsigned short* __restrict__ w1t,
                           const unsigned short* __restrict__ w2t,
                           const float* __restrict__ b1,
                           const float* __restrict__ b2,
                           const float* __restrict__ dinv,
                           float* __restrict__ out,
                           unsigned short* __restrict__ xs) {
    __shared__ unsigned short sH[64][264];

    const int tid  = threadIdx.x;
    const int lane = tid & 63;
    const int w    = tid >> 6;
    const int wr   = w >> 1;
    const int wc   = w & 1;
    const int l15  = lane & 15;
    const int l4   = lane >> 4;
    const int item0 = blockIdx.x * 64;

    f32x4 acc[2][8];
    #pragma unroll
    for (int i = 0; i < 2; ++i)
        #pragma unroll
        for (int j = 0; j < 8; ++j) acc[i][j] = (f32x4)0.0f;

    for (int kk = 0; kk < 16; ++kk) {
        const int kbase = kk * 32 + l4 * 8;
        bf16x8 afrag[2];
        #pragma unroll
        for (int rf = 0; rf < 2; ++rf) {
            int row = item0 + wr * 32 + rf * 16 + l15;
            row = min(row, NUM_ITEM - 1);
            const float4* ap = reinterpret_cast<const float4*>(feats + (size_t)row * FEAT_DIM + kbase);
            float4 x0 = ap[0], x1 = ap[1];
            BF8 t;
            t.u[0] = f2bf_rne(x0.x); t.u[1] = f2bf_rne(x0.y);
            t.u[2] = f2bf_rne(x0.z); t.u[3] = f2bf_rne(x0.w);
            t.u[4] = f2bf_rne(x1.x); t.u[5] = f2bf_rne(x1.y);
            t.u[6] = f2bf_rne(x1.z); t.u[7] = f2bf_rne(x1.w);
            afrag[rf] = t.b;
        }
        #pragma unroll
        for (int cf = 0; cf < 8; ++cf) {
            int colc = wc * 128 + cf * 16 + l15;
            BF8 t;
            t.u = *reinterpret_cast<const ushort8v*>(w1t + (size_t)colc * FEAT_DIM + kbase);
            acc[0][cf] = __builtin_amdgcn_mfma_f32_16x16x32_bf16(afrag[0], t.b, acc[0][cf], 0, 0, 0);
            acc[1][cf] = __builtin_amdgcn_mfma_f32_16x16x32_bf16(afrag[1], t.b, acc[1][cf], 0, 0, 0);
        }
    }

    #pragma unroll
    for (int rf = 0; rf < 2; ++rf) {
        #pragma unroll
        for (int cf = 0; cf < 8; ++cf) {
            int colc = wc * 128 + cf * 16 + l15;
            float bias = b1[colc];
            #pragma unroll
            for (int r = 0; r < 4; ++r) {
                int lrow = wr * 32 + rf * 16 + l4 * 4 + r;
                float h = acc[rf][cf][r] + bias;
                h = h > 0.0f ? h : 0.01f * h;
                sH[lrow][colc] = f2bf_rne(h);
            }
        }
    }
    __syncthreads();

    f32x4 acc2[4];
    #pragma unroll
    for (int j = 0; j < 4; ++j) acc2[j] = (f32x4)0.0f;

    for (int kk = 0; kk < 8; ++kk) {
        const int kbase = kk * 32 + l4 * 8;
        BF8 ta;
        ta.u = *reinterpret_cast<const ushort8v*>(&sH[w * 16 + l15][kbase]);
        #pragma unroll
        for (int cf = 0; cf < 4; ++cf) {
            int colc = cf * 16 + l15;
            BF8 tb;
            tb.u = *reinterpret_cast<const ushort8v*>(w2t + (size_t)colc * HID + kbase);
            acc2[cf] = __builtin_amdgcn_mfma_f32_16x16x32_bf16(ta.b, tb.b, acc2[cf], 0, 0, 0);
        }
    }

    #pragma unroll
    for (int cf = 0; cf < 4; ++cf) {
        int colc = cf * 16 + l15;
        float bias = b2[colc];
        #pragma unroll
        for (int r = 0; r < 4; ++r) {
            int item = item0 + w * 16 + l4 * 4 + r;
            if (item < NUM_ITEM) {
                int node = NUM_USER + item;
                float v = acc2[cf][r] + bias;
                out[(size_t)node * DLAT + colc] = v;
                xs [(size_t)node * DLAT + colc] = f2bf_rne(v * dinv[node]);
            }
        }
    }
}

// ---------------- user init: out = pref, xs = bf16(pref * dinv) ----------------
__global__ void pref_init(const float* __restrict__ pref, const float* __restrict__ dinv,
                          float* __restrict__ out, unsigned short* __restrict__ xs, int n4) {
    int i = blockIdx.x * blockDim.x + threadIdx.x;  // float4 index over NUM_USER*64/4
    if (i < n4) {
        float4 v = reinterpret_cast<const float4*>(pref)[i];
        float di = dinv[i >> 4];
        reinterpret_cast<float4*>(out)[i] = v;
        uint2 p;
        p.x = (unsigned)f2bf_rne(v.x * di) | ((unsigned)f2bf_rne(v.y * di) << 16);
        p.y = (unsigned)f2bf_rne(v.z * di) | ((unsigned)f2bf_rne(v.w * di) << 16);
        *reinterpret_cast<uint2*>(xs + (size_t)i * 4) = p;
    }
}

// ---------------- CSR gather hop (bf16 state): one wave per node ----------------
// lane = (g, r16): g = lane>>4 picks neighbor mod 4, r16 = lane&15 handles dims 4*r16..4*r16+3.
// One load instruction covers 4 rows (16 lanes x 8B = 128B row); unroll x4 => 16 rows in flight.
__launch_bounds__(256)
__global__ void hop_csr(const int* __restrict__ rowptr, const int* __restrict__ col,
                        const float* __restrict__ dinv, const unsigned short* __restrict__ xs,
                        float* __restrict__ out, unsigned short* __restrict__ xs_next,
                        int is_final, int n) {
    const int wave = (blockIdx.x * blockDim.x + threadIdx.x) >> 6;
    const int lane = threadIdx.x & 63;
    if (wave >= n) return;
    const int r0  = rowptr[wave];
    const int r1  = rowptr[wave + 1];
    const int g   = lane >> 4;
    const int r16 = lane & 15;

    float s0 = 0.0f, s1 = 0.0f, s2 = 0.0f, s3 = 0.0f;

    for (int base = r0; base < r1; base += 64) {
        int rem = r1 - base; if (rem > 64) rem = 64;
        int cvec = (lane < rem) ? col[base + lane] : 0;
        int j = 0;
        // 16 rows per body: 4 hoisted shfls + 4 independent dwordx2 loads
        for (; j + 16 <= rem; j += 16) {
            int c0 = __shfl(cvec, j + g);
            int c1 = __shfl(cvec, j + 4 + g);
            int c2 = __shfl(cvec, j + 8 + g);
            int c3 = __shfl(cvec, j + 12 + g);
            uint2 v0 = *reinterpret_cast<const uint2*>(xs + (size_t)c0 * DLAT + 4 * r16);
            uint2 v1 = *reinterpret_cast<const uint2*>(xs + (size_t)c1 * DLAT + 4 * r16);
            uint2 v2 = *reinterpret_cast<const uint2*>(xs + (size_t)c2 * DLAT + 4 * r16);
            uint2 v3 = *reinterpret_cast<const uint2*>(xs + (size_t)c3 * DLAT + 4 * r16);
            s0 += bf_lo(v0.x); s1 += bf_hi(v0.x); s2 += bf_lo(v0.y); s3 += bf_hi(v0.y);
            s0 += bf_lo(v1.x); s1 += bf_hi(v1.x); s2 += bf_lo(v1.y); s3 += bf_hi(v1.y);
            s0 += bf_lo(v2.x); s1 += bf_hi(v2.x); s2 += bf_lo(v2.y); s3 += bf_hi(v2.y);
            s0 += bf_lo(v3.x); s1 += bf_hi(v3.x); s2 += bf_lo(v3.y); s3 += bf_hi(v3.y);
        }
        for (; j + 4 <= rem; j += 4) {
            int c = __shfl(cvec, j + g);
            uint2 v = *reinterpret_cast<const uint2*>(xs + (size_t)c * DLAT + 4 * r16);
            s0 += bf_lo(v.x); s1 += bf_hi(v.x); s2 += bf_lo(v.y); s3 += bf_hi(v.y);
        }
        int tail = rem - j;  // 0..3
        if (tail > 0) {
            int jj = j + g;
            int cj = __shfl(cvec, jj < rem ? jj : (rem - 1));
            if (jj < rem) {
                uint2 v = *reinterpret_cast<const uint2*>(xs + (size_t)cj * DLAT + 4 * r16);
                s0 += bf_lo(v.x); s1 += bf_hi(v.x); s2 += bf_lo(v.y); s3 += bf_hi(v.y);
            }
        }
    }

    // reduce across the 4 groups (lanes with same r16)
    s0 += __shfl_xor(s0, 16); s0 += __shfl_xor(s0, 32);
    s1 += __shfl_xor(s1, 16); s1 += __shfl_xor(s1, 32);
    s2 += __shfl_xor(s2, 16); s2 += __shfl_xor(s2, 32);
    s3 += __shfl_xor(s3, 16); s3 += __shfl_xor(s3, 32);

    if (g == 0) {
        float di = dinv[wave];
        float y0 = di * s0, y1 = di * s1, y2 = di * s2, y3 = di * s3;
        size_t o = (size_t)wave * DLAT + 4 * r16;
        float4 prev = *reinterpret_cast<const float4*>(out + o);
        if (is_final) {
            float4 wv;
            wv.x = (prev.x + y0) * (1.0f / 3.0f);
            wv.y = (prev.y + y1) * (1.0f / 3.0f);
            wv.z = (prev.z + y2) * (1.0f / 3.0f);
            wv.w = (prev.w + y3) * (1.0f / 3.0f);
            *reinterpret_cast<float4*>(out + o) = wv;
        } else {
            float4 wv;
            wv.x = prev.x + y0;
            wv.y = prev.y + y1;
            wv.z = prev.z + y2;
            wv.w = prev.w + y3;
            *reinterpret_cast<float4*>(out + o) = wv;
            uint2 p;
            p.x = (unsigned)f2bf_rne(di * y0) | ((unsigned)f2bf_rne(di * y1) << 16);
            p.y = (unsigned)f2bf_rne(di * y2) | ((unsigned)f2bf_rne(di * y3) << 16);
            *reinterpret_cast<uint2*>(xs_next + o) = p;
        }
    }
}

extern "C" void kernel_launch(void* const* d_in, const int* in_sizes, int n_in,
                              void* d_out, int out_size, void* d_ws, size_t ws_size,
                              hipStream_t stream) {
    const float* feats = (const float*)d_in[0];
    const int*   eidx  = (const int*)d_in[1];
    const float* pref  = (const float*)d_in[2];
    const float* W1    = (const float*)d_in[3];
    const float* b1    = (const float*)d_in[4];
    const float* W2    = (const float*)d_in[5];
    const float* b2    = (const float*)d_in[6];

    const int E = in_sizes[1] / 2;
    const int* src = eidx;
    const int* dst = eidx + E;

    char* ws = (char*)d_ws;
    size_t off = 0;
    auto alloc = [&](size_t bytes) -> void* {
        void* p = ws + off;
        off += (bytes + 255) & ~(size_t)255;
        return p;
    };
    const size_t xsbytes = (size_t)NUM_NODES * DLAT * sizeof(unsigned short);
    unsigned short* xsA = (unsigned short*)alloc(xsbytes);
    unsigned short* xsB = (unsigned short*)alloc(xsbytes);
    int*      colbf = (int*)alloc((size_t)E * sizeof(int));
    unsigned* pairs = (unsigned*)alloc((size_t)E * sizeof(unsigned));
    float*    dinv  = (float*)alloc((size_t)NUM_NODES * sizeof(float));
    int*      rowp  = (int*)alloc((size_t)(NUM_NODES + 1) * sizeof(int));
    int*      bhist = (int*)alloc((size_t)NBUCK * sizeof(int));
    int*      bbase = (int*)alloc((size_t)NBUCK * sizeof(int));
    int*      gfill = (int*)alloc((size_t)NBUCK * sizeof(int));
    unsigned short* w1t = (unsigned short*)alloc((size_t)FEAT_DIM * HID * 2);
    unsigned short* w2t = (unsigned short*)alloc((size_t)HID * DLAT * 2);
    float* out = (float*)d_out;

    // bucketed CSR build
    hipMemsetAsync(bhist, 0, (size_t)NBUCK * sizeof(int), stream);
    hipMemsetAsync(gfill, 0, (size_t)NBUCK * sizeof(int), stream);
    bucket_hist<<<512, 256, 0, stream>>>(src, bhist, E);
    bucket_scan<<<1, 512, 0, stream>>>(bhist, bbase);
    bucket_scatter<<<(E + CHUNK - 1) / CHUNK, 256, 0, stream>>>(src, dst, bbase, gfill, pairs, E);
    csr_build<<<NBUCK, 256, 0, stream>>>(bhist, bbase, pairs, rowp, dinv, colbf);

    // weights -> bf16 transposed
    convert_weights<<<(FEAT_DIM * HID + HID * DLAT + 255) / 256, 256, 0, stream>>>(W1, W2, w1t, w2t);

    // x0: item MLP + preference; out = x0, xsA = bf16(dinv * x0)
    mlp_kernel<<<(NUM_ITEM + 63) / 64, 256, 0, stream>>>(feats, w1t, w2t, b1, b2, dinv, out, xsA);
    pref_init<<<(NUM_USER * DLAT / 4 + 255) / 256, 256, 0, stream>>>(pref, dinv, out, xsA, NUM_USER * DLAT / 4);

    // hop 1: y1 = dinv * (A xsA); out += y1; xsB = bf16(dinv * y1)
    const int hopBlocks = (NUM_NODES * 64 + 255) / 256;
    hop_csr<<<hopBlocks, 256, 0, stream>>>(rowp, colbf, dinv, xsA, out, xsB, 0, NUM_NODES);

    // hop 2: y2 = dinv * (A xsB); out = (out + y2) / 3
    hop_csr<<<hopBlocks, 256, 0, stream>>>(rowp, colbf, dinv, xsB, out, nullptr, 1, NUM_NODES);
}

// Round 6
// 507.051 us; speedup vs baseline: 6.1243x; 1.0892x over previous
//
#include <hip/hip_runtime.h>

#define NUM_USER 100000
#define NUM_ITEM 50000
#define NUM_NODES 150000
#define FEAT_DIM 512
#define DLAT 64
#define HID 256

// bucketed CSR build
#define BSHIFT 9
#define BWIDTH 512                       // nodes per bucket
#define NBUCK 293                        // ceil(150000/512)
#define CHUNK 4096                       // edges per bucket_scatter block

typedef float f32x4 __attribute__((ext_vector_type(4)));
typedef __bf16 bf16x8 __attribute__((ext_vector_type(8)));
typedef unsigned short ushort8v __attribute__((ext_vector_type(8)));

union BF8 { ushort8v u; bf16x8 b; };

__device__ inline unsigned short f2bf_rne(float f) {
    unsigned u = __float_as_uint(f);
    u += 0x7FFFu + ((u >> 16) & 1u);
    return (unsigned short)(u >> 16);
}

__device__ inline float bf_lo(unsigned v) { return __uint_as_float(v << 16); }
__device__ inline float bf_hi(unsigned v) { return __uint_as_float(v & 0xffff0000u); }

// ---------------- pass A: bucket histogram ----------------
__global__ void bucket_hist(const int* __restrict__ src, int* __restrict__ bhist, int E) {
    __shared__ int h[NBUCK];
    for (int i = threadIdx.x; i < NBUCK; i += blockDim.x) h[i] = 0;
    __syncthreads();
    const int stride = gridDim.x * blockDim.x;
    for (int i = blockIdx.x * blockDim.x + threadIdx.x; i < E; i += stride)
        atomicAdd(&h[src[i] >> BSHIFT], 1);
    __syncthreads();
    for (int i = threadIdx.x; i < NBUCK; i += blockDim.x)
        if (h[i]) atomicAdd(&bhist[i], h[i]);
}

// ---------------- pass A2: exclusive scan of bucket histogram ----------------
__global__ void bucket_scan(const int* __restrict__ bhist, int* __restrict__ bbase) {
    __shared__ int s[512];
    const int t = threadIdx.x;
    const int v = (t < NBUCK) ? bhist[t] : 0;
    s[t] = v;
    __syncthreads();
    for (int off = 1; off < 512; off <<= 1) {
        int add = (t >= off) ? s[t - off] : 0;
        __syncthreads();
        s[t] += add;
        __syncthreads();
    }
    if (t < NBUCK) bbase[t] = s[t] - v;  // exclusive
}

// ---------------- pass B: scatter edges into bucket-grouped packed pairs ----------------
// pair = (s & 511) << 18 | d   (d < 2^18)
__global__ void bucket_scatter(const int* __restrict__ src, const int* __restrict__ dst,
                               const int* __restrict__ bbase, int* __restrict__ gfill,
                               unsigned* __restrict__ pairs, int E) {
    __shared__ int h[NBUCK];
    __shared__ int base[NBUCK];
    const int t = threadIdx.x;
    for (int i = t; i < NBUCK; i += blockDim.x) h[i] = 0;
    __syncthreads();
    const int i0 = blockIdx.x * CHUNK;
    const int i1 = min(i0 + CHUNK, E);
    for (int i = i0 + t; i < i1; i += blockDim.x)
        atomicAdd(&h[src[i] >> BSHIFT], 1);
    __syncthreads();
    for (int i = t; i < NBUCK; i += blockDim.x) {
        int c = h[i];
        base[i] = c ? (bbase[i] + atomicAdd(&gfill[i], c)) : 0;
        h[i] = 0;
    }
    __syncthreads();
    for (int i = i0 + t; i < i1; i += blockDim.x) {
        int s = src[i], d = dst[i];
        int b = s >> BSHIFT;
        int pos = atomicAdd(&h[b], 1);
        pairs[base[b] + pos] = ((unsigned)(s & (BWIDTH - 1)) << 18) | (unsigned)d;
    }
}

// ---------------- pass CD: per-bucket degree count + rowptr/dinv + CSR fill ----------------
__launch_bounds__(256)
__global__ void csr_build(const int* __restrict__ bhist, const int* __restrict__ bbase,
                          const unsigned* __restrict__ pairs,
                          int* __restrict__ rowptr, float* __restrict__ dinv,
                          int* __restrict__ col) {
    __shared__ int degl[BWIDTH];
    __shared__ int offl[BWIDTH];
    const int b = blockIdx.x;
    const int t = threadIdx.x;
    const int node0 = b << BSHIFT;
    const int e0 = bbase[b];
    const int ecnt = bhist[b];

    degl[t] = 0; degl[t + 256] = 0;
    __syncthreads();
    for (int i = t; i < ecnt; i += 256)
        atomicAdd(&degl[pairs[e0 + i] >> 18], 1);
    __syncthreads();

    // inclusive scan of degl[0..511] (2 elements per thread)
    const int v0 = degl[t], v1 = degl[t + 256];
    offl[t] = v0; offl[t + 256] = v1;
    __syncthreads();
    for (int off = 1; off < 512; off <<= 1) {
        int a0 = (t >= off) ? offl[t - off] : 0;
        int a1 = offl[t + 256 - off];
        __syncthreads();
        offl[t] += a0;
        offl[t + 256] += a1;
        __syncthreads();
    }
    const int excl0 = offl[t] - v0;
    const int excl1 = offl[t + 256] - v1;

    const int n0 = node0 + t, n1 = node0 + t + 256;
    if (n0 < NUM_NODES) {
        rowptr[n0] = e0 + excl0;
        dinv[n0] = v0 > 0 ? rsqrtf((float)v0) : 0.0f;
    }
    if (n1 < NUM_NODES) {
        rowptr[n1] = e0 + excl1;
        dinv[n1] = v1 > 0 ? rsqrtf((float)v1) : 0.0f;
    }
    if (b == NBUCK - 1 && t == 0) rowptr[NUM_NODES] = e0 + ecnt;
    __syncthreads();

    // reuse: offl <- exclusive base, degl <- fill counters
    offl[t] = excl0; offl[t + 256] = excl1;
    degl[t] = 0;     degl[t + 256] = 0;
    __syncthreads();
    for (int i = t; i < ecnt; i += 256) {
        unsigned p = pairs[e0 + i];
        int sl = p >> 18;
        int d  = (int)(p & 0x3FFFFu);
        int pos = atomicAdd(&degl[sl], 1);
        col[e0 + offl[sl] + pos] = d;
    }
}

// ---------------- weight conversion (transpose to bf16) ----------------
__global__ void convert_weights(const float* __restrict__ W1, const float* __restrict__ W2,
                                unsigned short* __restrict__ w1t, unsigned short* __restrict__ w2t) {
    int idx = blockIdx.x * blockDim.x + threadIdx.x;
    if (idx < FEAT_DIM * HID) {
        int k = idx / HID, n = idx % HID;
        w1t[(size_t)n * FEAT_DIM + k] = f2bf_rne(W1[idx]);
    } else {
        int j = idx - FEAT_DIM * HID;
        if (j < HID * DLAT) {
            int k = j / DLAT, n = j % DLAT;
            w2t[(size_t)n * HID + k] = f2bf_rne(W2[j]);
        }
    }
}

// ---------------- GEMM1: H = leakyrelu(feats @ W1 + b1), bf16 out ----------------
// 512 threads, 8 waves (2x4), tile 128x256, BK=32.
// LDS: sA [k4][128 rows][16B] = 8 KB at off 0; sB [k4][256 cols][16B] = 16 KB at off 8192.
// Epilogue reuses the full 64 KB as sH[128][256] u16 for coalesced H stores.
__launch_bounds__(512, 4)
__global__ void gemm1_kernel(const float* __restrict__ feats,
                             const unsigned short* __restrict__ w1t,
                             const float* __restrict__ b1,
                             unsigned short* __restrict__ H) {
    __shared__ __align__(16) unsigned char smem[65536];
    unsigned short* sA = (unsigned short*)smem;            // ushort units
    unsigned short* sB = (unsigned short*)(smem + 8192);
    unsigned short* sH = (unsigned short*)smem;

    const int t    = threadIdx.x;
    const int lane = t & 63;
    const int w    = t >> 6;        // 0..7
    const int wr   = w >> 2;        // 0..1: rows 64*wr
    const int wc   = w & 3;         // 0..3: cols 64*wc
    const int l15  = lane & 15;
    const int l4   = lane >> 4;
    const int item0 = blockIdx.x * 128;

    // A staging role: thread t -> k4 = t>>7, row = t&127
    const int a_k4  = t >> 7;
    const int a_row = t & 127;
    const int a_rowg = min(item0 + a_row, NUM_ITEM - 1);
    const float* a_src = feats + (size_t)a_rowg * FEAT_DIM + a_k4 * 8;
    unsigned short* a_dst = sA + a_k4 * 1024 + a_row * 8;

    // B staging role: thread t -> col = t&255, k4 pair = (t>>8)*2
    const int b_col = t & 255;
    const int b_kq  = (t >> 8) * 2;
    const unsigned short* b_src = w1t + (size_t)b_col * FEAT_DIM + b_kq * 8;
    unsigned short* b_dst = sB + b_kq * 2048 + b_col * 8;

    f32x4 acc[4][4];
    #pragma unroll
    for (int i = 0; i < 4; ++i)
        #pragma unroll
        for (int j = 0; j < 4; ++j) acc[i][j] = (f32x4)0.0f;

    for (int kk = 0; kk < 16; ++kk) {
        const int kbase = kk * 32;
        // stage A: 8 fp32 -> bf16x8 -> one ds_write_b128
        float4 f0 = *reinterpret_cast<const float4*>(a_src + kbase);
        float4 f1 = *reinterpret_cast<const float4*>(a_src + kbase + 4);
        BF8 ta;
        ta.u[0] = f2bf_rne(f0.x); ta.u[1] = f2bf_rne(f0.y);
        ta.u[2] = f2bf_rne(f0.z); ta.u[3] = f2bf_rne(f0.w);
        ta.u[4] = f2bf_rne(f1.x); ta.u[5] = f2bf_rne(f1.y);
        ta.u[6] = f2bf_rne(f1.z); ta.u[7] = f2bf_rne(f1.w);
        *reinterpret_cast<ushort8v*>(a_dst) = ta.u;
        // stage B: two 16B chunks (k4, k4+1)
        ushort8v bv0 = *reinterpret_cast<const ushort8v*>(b_src + kbase);
        ushort8v bv1 = *reinterpret_cast<const ushort8v*>(b_src + kbase + 8);
        *reinterpret_cast<ushort8v*>(b_dst)        = bv0;
        *reinterpret_cast<ushort8v*>(b_dst + 2048) = bv1;
        __syncthreads();

        // compute: wave (wr,wc) does rows wr*64.., cols wc*64..
        BF8 af[4];
        #pragma unroll
        for (int rf = 0; rf < 4; ++rf)
            af[rf].u = *reinterpret_cast<const ushort8v*>(sA + l4 * 1024 + (wr * 64 + rf * 16 + l15) * 8);
        #pragma unroll
        for (int cf = 0; cf < 4; ++cf) {
            BF8 bf;
            bf.u = *reinterpret_cast<const ushort8v*>(sB + l4 * 2048 + (wc * 64 + cf * 16 + l15) * 8);
            #pragma unroll
            for (int rf = 0; rf < 4; ++rf)
                acc[rf][cf] = __builtin_amdgcn_mfma_f32_16x16x32_bf16(af[rf].b, bf.b, acc[rf][cf], 0, 0, 0);
        }
        __syncthreads();
    }

    // epilogue: bias + leaky -> sH (u16 scatter), then coalesced global stores
    float bias[4];
    #pragma unroll
    for (int cf = 0; cf < 4; ++cf) bias[cf] = b1[wc * 64 + cf * 16 + l15];

    #pragma unroll
    for (int rf = 0; rf < 4; ++rf) {
        #pragma unroll
        for (int cf = 0; cf < 4; ++cf) {
            const int colc = wc * 64 + cf * 16 + l15;
            #pragma unroll
            for (int r = 0; r < 4; ++r) {
                const int row = wr * 64 + rf * 16 + l4 * 4 + r;
                float h = acc[rf][cf][r] + bias[cf];
                h = h > 0.0f ? h : 0.01f * h;
                sH[row * 256 + colc] = f2bf_rne(h);
            }
        }
    }
    __syncthreads();

    #pragma unroll
    for (int p = 0; p < 8; ++p) {
        const int idx  = p * 512 + t;     // 0..4095
        const int row  = idx >> 5;        // 0..127
        const int chnk = idx & 31;        // 8 ushorts each
        if (item0 + row < NUM_ITEM) {
            *reinterpret_cast<ushort8v*>(H + (size_t)(item0 + row) * HID + chnk * 8) =
                *reinterpret_cast<const ushort8v*>(sH + row * 256 + chnk * 8);
        }
    }
}

// ---------------- GEMM2: out_items = H @ W2 + b2 ; xs = bf16(dinv * out) ----------------
__launch_bounds__(256)
__global__ void gemm2_kernel(const unsigned short* __restrict__ H,
                             const unsigned short* __restrict__ w2t,
                             const float* __restrict__ b2,
                             const float* __restrict__ dinv,
                             float* __restrict__ out,
                             unsigned short* __restrict__ xs) {
    const int tid  = threadIdx.x;
    const int lane = tid & 63;
    const int w    = tid >> 6;
    const int l15  = lane & 15;
    const int l4   = lane >> 4;
    const int item0 = blockIdx.x * 64;

    const int rowg = min(item0 + w * 16 + l15, NUM_ITEM - 1);
    const unsigned short* hrow = H + (size_t)rowg * HID;

    f32x4 acc2[4];
    #pragma unroll
    for (int j = 0; j < 4; ++j) acc2[j] = (f32x4)0.0f;

    for (int kk = 0; kk < 8; ++kk) {
        const int kbase = kk * 32 + l4 * 8;
        BF8 ta;
        ta.u = *reinterpret_cast<const ushort8v*>(hrow + kbase);
        #pragma unroll
        for (int cf = 0; cf < 4; ++cf) {
            BF8 tb;
            tb.u = *reinterpret_cast<const ushort8v*>(w2t + (size_t)(cf * 16 + l15) * HID + kbase);
            acc2[cf] = __builtin_amdgcn_mfma_f32_16x16x32_bf16(ta.b, tb.b, acc2[cf], 0, 0, 0);
        }
    }

    #pragma unroll
    for (int cf = 0; cf < 4; ++cf) {
        const int colc = cf * 16 + l15;
        const float bias = b2[colc];
        #pragma unroll
        for (int r = 0; r < 4; ++r) {
            const int item = item0 + w * 16 + l4 * 4 + r;
            if (item < NUM_ITEM) {
                const int node = NUM_USER + item;
                float v = acc2[cf][r] + bias;
                out[(size_t)node * DLAT + colc] = v;
                xs [(size_t)node * DLAT + colc] = f2bf_rne(v * dinv[node]);
            }
        }
    }
}

// ---------------- user init: out = pref, xs = bf16(pref * dinv) ----------------
__global__ void pref_init(const float* __restrict__ pref, const float* __restrict__ dinv,
                          float* __restrict__ out, unsigned short* __restrict__ xs, int n4) {
    int i = blockIdx.x * blockDim.x + threadIdx.x;  // float4 index over NUM_USER*64/4
    if (i < n4) {
        float4 v = reinterpret_cast<const float4*>(pref)[i];
        float di = dinv[i >> 4];
        reinterpret_cast<float4*>(out)[i] = v;
        uint2 p;
        p.x = (unsigned)f2bf_rne(v.x * di) | ((unsigned)f2bf_rne(v.y * di) << 16);
        p.y = (unsigned)f2bf_rne(v.z * di) | ((unsigned)f2bf_rne(v.w * di) << 16);
        *reinterpret_cast<uint2*>(xs + (size_t)i * 4) = p;
    }
}

// ---------------- CSR gather hop (bf16 state): one wave per node ----------------
// lane = (g, r16): g = lane>>4 picks neighbor mod 4, r16 = lane&15 handles dims 4*r16..4*r16+3.
// One load instruction covers 4 rows (16 lanes x 8B = 128B row); unroll x4 => 16 rows in flight.
__launch_bounds__(256)
__global__ void hop_csr(const int* __restrict__ rowptr, const int* __restrict__ col,
                        const float* __restrict__ dinv, const unsigned short* __restrict__ xs,
                        float* __restrict__ out, unsigned short* __restrict__ xs_next,
                        int is_final, int n) {
    const int wave = (blockIdx.x * blockDim.x + threadIdx.x) >> 6;
    const int lane = threadIdx.x & 63;
    if (wave >= n) return;
    const int r0  = rowptr[wave];
    const int r1  = rowptr[wave + 1];
    const int g   = lane >> 4;
    const int r16 = lane & 15;

    float s0 = 0.0f, s1 = 0.0f, s2 = 0.0f, s3 = 0.0f;

    for (int base = r0; base < r1; base += 64) {
        int rem = r1 - base; if (rem > 64) rem = 64;
        int cvec = (lane < rem) ? col[base + lane] : 0;
        int j = 0;
        // 16 rows per body: 4 hoisted shfls + 4 independent dwordx2 loads
        for (; j + 16 <= rem; j += 16) {
            int c0 = __shfl(cvec, j + g);
            int c1 = __shfl(cvec, j + 4 + g);
            int c2 = __shfl(cvec, j + 8 + g);
            int c3 = __shfl(cvec, j + 12 + g);
            uint2 v0 = *reinterpret_cast<const uint2*>(xs + (size_t)c0 * DLAT + 4 * r16);
            uint2 v1 = *reinterpret_cast<const uint2*>(xs + (size_t)c1 * DLAT + 4 * r16);
            uint2 v2 = *reinterpret_cast<const uint2*>(xs + (size_t)c2 * DLAT + 4 * r16);
            uint2 v3 = *reinterpret_cast<const uint2*>(xs + (size_t)c3 * DLAT + 4 * r16);
            s0 += bf_lo(v0.x); s1 += bf_hi(v0.x); s2 += bf_lo(v0.y); s3 += bf_hi(v0.y);
            s0 += bf_lo(v1.x); s1 += bf_hi(v1.x); s2 += bf_lo(v1.y); s3 += bf_hi(v1.y);
            s0 += bf_lo(v2.x); s1 += bf_hi(v2.x); s2 += bf_lo(v2.y); s3 += bf_hi(v2.y);
            s0 += bf_lo(v3.x); s1 += bf_hi(v3.x); s2 += bf_lo(v3.y); s3 += bf_hi(v3.y);
        }
        for (; j + 4 <= rem; j += 4) {
            int c = __shfl(cvec, j + g);
            uint2 v = *reinterpret_cast<const uint2*>(xs + (size_t)c * DLAT + 4 * r16);
            s0 += bf_lo(v.x); s1 += bf_hi(v.x); s2 += bf_lo(v.y); s3 += bf_hi(v.y);
        }
        int tail = rem - j;  // 0..3
        if (tail > 0) {
            int jj = j + g;
            int cj = __shfl(cvec, jj < rem ? jj : (rem - 1));
            if (jj < rem) {
                uint2 v = *reinterpret_cast<const uint2*>(xs + (size_t)cj * DLAT + 4 * r16);
                s0 += bf_lo(v.x); s1 += bf_hi(v.x); s2 += bf_lo(v.y); s3 += bf_hi(v.y);
            }
        }
    }

    // reduce across the 4 groups (lanes with same r16)
    s0 += __shfl_xor(s0, 16); s0 += __shfl_xor(s0, 32);
    s1 += __shfl_xor(s1, 16); s1 += __shfl_xor(s1, 32);
    s2 += __shfl_xor(s2, 16); s2 += __shfl_xor(s2, 32);
    s3 += __shfl_xor(s3, 16); s3 += __shfl_xor(s3, 32);

    if (g == 0) {
        float di = dinv[wave];
        float y0 = di * s0, y1 = di * s1, y2 = di * s2, y3 = di * s3;
        size_t o = (size_t)wave * DLAT + 4 * r16;
        float4 prev = *reinterpret_cast<const float4*>(out + o);
        if (is_final) {
            float4 wv;
            wv.x = (prev.x + y0) * (1.0f / 3.0f);
            wv.y = (prev.y + y1) * (1.0f / 3.0f);
            wv.z = (prev.z + y2) * (1.0f / 3.0f);
            wv.w = (prev.w + y3) * (1.0f / 3.0f);
            *reinterpret_cast<float4*>(out + o) = wv;
        } else {
            float4 wv;
            wv.x = prev.x + y0;
            wv.y = prev.y + y1;
            wv.z = prev.z + y2;
            wv.w = prev.w + y3;
            *reinterpret_cast<float4*>(out + o) = wv;
            uint2 p;
            p.x = (unsigned)f2bf_rne(di * y0) | ((unsigned)f2bf_rne(di * y1) << 16);
            p.y = (unsigned)f2bf_rne(di * y2) | ((unsigned)f2bf_rne(di * y3) << 16);
            *reinterpret_cast<uint2*>(xs_next + o) = p;
        }
    }
}

extern "C" void kernel_launch(void* const* d_in, const int* in_sizes, int n_in,
                              void* d_out, int out_size, void* d_ws, size_t ws_size,
                              hipStream_t stream) {
    const float* feats = (const float*)d_in[0];
    const int*   eidx  = (const int*)d_in[1];
    const float* pref  = (const float*)d_in[2];
    const float* W1    = (const float*)d_in[3];
    const float* b1    = (const float*)d_in[4];
    const float* W2    = (const float*)d_in[5];
    const float* b2    = (const float*)d_in[6];

    const int E = in_sizes[1] / 2;
    const int* src = eidx;
    const int* dst = eidx + E;

    char* ws = (char*)d_ws;
    size_t off = 0;
    auto alloc = [&](size_t bytes) -> void* {
        void* p = ws + off;
        off += (bytes + 255) & ~(size_t)255;
        return p;
    };
    const size_t xsbytes = (size_t)NUM_NODES * DLAT * sizeof(unsigned short);
    unsigned short* xsA = (unsigned short*)alloc(xsbytes);
    unsigned short* xsB = (unsigned short*)alloc(xsbytes);
    int*      colbf = (int*)alloc((size_t)E * sizeof(int));
    unsigned* pairs = (unsigned*)alloc((size_t)E * sizeof(unsigned));  // reused as H after csr_build
    float*    dinv  = (float*)alloc((size_t)NUM_NODES * sizeof(float));
    int*      rowp  = (int*)alloc((size_t)(NUM_NODES + 1) * sizeof(int));
    int*      bhist = (int*)alloc((size_t)NBUCK * sizeof(int));
    int*      bbase = (int*)alloc((size_t)NBUCK * sizeof(int));
    int*      gfill = (int*)alloc((size_t)NBUCK * sizeof(int));
    unsigned short* w1t = (unsigned short*)alloc((size_t)FEAT_DIM * HID * 2);
    unsigned short* w2t = (unsigned short*)alloc((size_t)HID * DLAT * 2);
    float* out = (float*)d_out;
    unsigned short* H = (unsigned short*)pairs;  // 50000*256*2 = 25.6 MB == E*4

    // bucketed CSR build
    hipMemsetAsync(bhist, 0, (size_t)NBUCK * sizeof(int), stream);
    hipMemsetAsync(gfill, 0, (size_t)NBUCK * sizeof(int), stream);
    bucket_hist<<<512, 256, 0, stream>>>(src, bhist, E);
    bucket_scan<<<1, 512, 0, stream>>>(bhist, bbase);
    bucket_scatter<<<(E + CHUNK - 1) / CHUNK, 256, 0, stream>>>(src, dst, bbase, gfill, pairs, E);
    csr_build<<<NBUCK, 256, 0, stream>>>(bhist, bbase, pairs, rowp, dinv, colbf);

    // weights -> bf16 transposed
    convert_weights<<<(FEAT_DIM * HID + HID * DLAT + 255) / 256, 256, 0, stream>>>(W1, W2, w1t, w2t);

    // item MLP as two tiled GEMMs (H overlays pairs, which is dead after csr_build)
    gemm1_kernel<<<(NUM_ITEM + 127) / 128, 512, 0, stream>>>(feats, w1t, b1, H);
    gemm2_kernel<<<(NUM_ITEM + 63) / 64, 256, 0, stream>>>(H, w2t, b2, dinv, out, xsA);
    pref_init<<<(NUM_USER * DLAT / 4 + 255) / 256, 256, 0, stream>>>(pref, dinv, out, xsA, NUM_USER * DLAT / 4);

    // hop 1: y1 = dinv * (A xsA); out += y1; xsB = bf16(dinv * y1)
    const int hopBlocks = (NUM_NODES * 64 + 255) / 256;
    hop_csr<<<hopBlocks, 256, 0, stream>>>(rowp, colbf, dinv, xsA, out, xsB, 0, NUM_NODES);

    // hop 2: y2 = dinv * (A xsB); out = (out + y2) / 3
    hop_csr<<<hopBlocks, 256, 0, stream>>>(rowp, colbf, dinv, xsB, out, nullptr, 1, NUM_NODES);
}

// Round 7
// 478.628 us; speedup vs baseline: 6.4880x; 1.0594x over previous
//
#include <hip/hip_runtime.h>

#define NUM_USER 100000
#define NUM_ITEM 50000
#define NUM_NODES 150000
#define FEAT_DIM 512
#define DLAT 64
#define HID 256

// bucketed CSR build
#define BSHIFT 9
#define BWIDTH 512                       // nodes per bucket
#define NBUCK 293                        // ceil(150000/512)
#define CPAIR 6144                       // pairs per bucket_scatter2 block (emits 12288 entries)

typedef float f32x4 __attribute__((ext_vector_type(4)));
typedef __bf16 bf16x8 __attribute__((ext_vector_type(8)));
typedef unsigned short ushort8v __attribute__((ext_vector_type(8)));

union BF8 { ushort8v u; bf16x8 b; };

__device__ inline unsigned short f2bf_rne(float f) {
    unsigned u = __float_as_uint(f);
    u += 0x7FFFu + ((u >> 16) & 1u);
    return (unsigned short)(u >> 16);
}

__device__ inline float bf_lo(unsigned v) { return __uint_as_float(v << 16); }
__device__ inline float bf_hi(unsigned v) { return __uint_as_float(v & 0xffff0000u); }

// ---------------- pass A: bucket histogram over undirected pairs ----------------
// pair (u,i) contributes deg to node u (user side) and node i (item side)
__global__ void bucket_hist2(const int* __restrict__ usrc, const int* __restrict__ idst,
                             int* __restrict__ bhist, int npair) {
    __shared__ int h[NBUCK];
    for (int i = threadIdx.x; i < NBUCK; i += blockDim.x) h[i] = 0;
    __syncthreads();
    const int stride = gridDim.x * blockDim.x;
    for (int i = blockIdx.x * blockDim.x + threadIdx.x; i < npair; i += stride) {
        atomicAdd(&h[usrc[i] >> BSHIFT], 1);
        atomicAdd(&h[idst[i] >> BSHIFT], 1);
    }
    __syncthreads();
    for (int i = threadIdx.x; i < NBUCK; i += blockDim.x)
        if (h[i]) atomicAdd(&bhist[i], h[i]);
}

// ---------------- pass A2: exclusive scan of bucket histogram ----------------
__global__ void bucket_scan(const int* __restrict__ bhist, int* __restrict__ bbase) {
    __shared__ int s[512];
    const int t = threadIdx.x;
    const int v = (t < NBUCK) ? bhist[t] : 0;
    s[t] = v;
    __syncthreads();
    for (int off = 1; off < 512; off <<= 1) {
        int add = (t >= off) ? s[t - off] : 0;
        __syncthreads();
        s[t] += add;
        __syncthreads();
    }
    if (t < NBUCK) bbase[t] = s[t] - v;  // exclusive
}

// ---------------- pass B: LDS-staged scatter into bucket-grouped packed pairs ----------------
// entry = (s_local << 18) | d  (d < 2^18). Each undirected pair emits 2 entries.
// Entries are staged in LDS grouped by bucket, then written out as wave-coalesced runs.
__launch_bounds__(256)
__global__ void bucket_scatter2(const int* __restrict__ usrc, const int* __restrict__ idst,
                                const int* __restrict__ bbase, int* __restrict__ gfill,
                                unsigned* __restrict__ pairs, int npair) {
    __shared__ unsigned stage[2 * CPAIR];   // 48 KB
    __shared__ int h[NBUCK];
    __shared__ int loff[NBUCK];
    __shared__ int gbase[NBUCK];
    __shared__ int offl[512];

    const int t = threadIdx.x;
    for (int i = t; i < NBUCK; i += 256) h[i] = 0;
    __syncthreads();

    const int p0 = blockIdx.x * CPAIR;
    const int p1 = min(p0 + CPAIR, npair);

    // count
    for (int j = p0 + t; j < p1; j += 256) {
        atomicAdd(&h[usrc[j] >> BSHIFT], 1);
        atomicAdd(&h[idst[j] >> BSHIFT], 1);
    }
    __syncthreads();

    // exclusive scan of h (293 slots, 2 per thread over 512)
    const int v0 = h[t];                              // t < 256 < NBUCK
    const int v1 = (t + 256 < NBUCK) ? h[t + 256] : 0;
    offl[t] = v0; offl[t + 256] = v1;
    __syncthreads();
    for (int off = 1; off < 512; off <<= 1) {
        int a0 = (t >= off) ? offl[t - off] : 0;
        int a1 = offl[t + 256 - off];
        __syncthreads();
        offl[t] += a0;
        offl[t + 256] += a1;
        __syncthreads();
    }
    loff[t] = offl[t] - v0;
    if (t + 256 < NBUCK) loff[t + 256] = offl[t + 256] - v1;
    __syncthreads();

    // claim one contiguous global run per non-empty bucket
    for (int i = t; i < NBUCK; i += 256) {
        int c = h[i];
        gbase[i] = c ? (bbase[i] + atomicAdd(&gfill[i], c)) : 0;
    }
    __syncthreads();
    for (int i = t; i < NBUCK; i += 256) h[i] = 0;
    __syncthreads();

    // place entries into LDS stage (re-read pairs; L2-hot)
    for (int j = p0 + t; j < p1; j += 256) {
        int u = usrc[j], v = idst[j];
        int bu = u >> BSHIFT, bv = v >> BSHIFT;
        int pu = atomicAdd(&h[bu], 1);
        stage[loff[bu] + pu] = ((unsigned)(u & (BWIDTH - 1)) << 18) | (unsigned)v;
        int pv = atomicAdd(&h[bv], 1);
        stage[loff[bv] + pv] = ((unsigned)(v & (BWIDTH - 1)) << 18) | (unsigned)u;
    }
    __syncthreads();

    // write out: one wave per bucket run, lane-consecutive (coalesced)
    const int wv = t >> 6, ln = t & 63;
    for (int b = wv; b < NBUCK; b += 4) {
        const int len = h[b];
        const int lo  = loff[b];
        unsigned* gp = pairs + gbase[b];
        for (int k = ln; k < len; k += 64) gp[k] = stage[lo + k];
    }
}

// ---------------- pass CD: per-bucket degree count + rowptr/dinv + CSR fill ----------------
__launch_bounds__(256)
__global__ void csr_build(const int* __restrict__ bhist, const int* __restrict__ bbase,
                          const unsigned* __restrict__ pairs,
                          int* __restrict__ rowptr, float* __restrict__ dinv,
                          int* __restrict__ col) {
    __shared__ int degl[BWIDTH];
    __shared__ int offl[BWIDTH];
    const int b = blockIdx.x;
    const int t = threadIdx.x;
    const int node0 = b << BSHIFT;
    const int e0 = bbase[b];
    const int ecnt = bhist[b];

    degl[t] = 0; degl[t + 256] = 0;
    __syncthreads();
    for (int i = t; i < ecnt; i += 256)
        atomicAdd(&degl[pairs[e0 + i] >> 18], 1);
    __syncthreads();

    // inclusive scan of degl[0..511] (2 elements per thread)
    const int v0 = degl[t], v1 = degl[t + 256];
    offl[t] = v0; offl[t + 256] = v1;
    __syncthreads();
    for (int off = 1; off < 512; off <<= 1) {
        int a0 = (t >= off) ? offl[t - off] : 0;
        int a1 = offl[t + 256 - off];
        __syncthreads();
        offl[t] += a0;
        offl[t + 256] += a1;
        __syncthreads();
    }
    const int excl0 = offl[t] - v0;
    const int excl1 = offl[t + 256] - v1;

    const int n0 = node0 + t, n1 = node0 + t + 256;
    if (n0 < NUM_NODES) {
        rowptr[n0] = e0 + excl0;
        dinv[n0] = v0 > 0 ? rsqrtf((float)v0) : 0.0f;
    }
    if (n1 < NUM_NODES) {
        rowptr[n1] = e0 + excl1;
        dinv[n1] = v1 > 0 ? rsqrtf((float)v1) : 0.0f;
    }
    if (b == NBUCK - 1 && t == 0) rowptr[NUM_NODES] = e0 + ecnt;
    __syncthreads();

    // reuse: offl <- exclusive base, degl <- fill counters
    offl[t] = excl0; offl[t + 256] = excl1;
    degl[t] = 0;     degl[t + 256] = 0;
    __syncthreads();
    for (int i = t; i < ecnt; i += 256) {
        unsigned p = pairs[e0 + i];
        int sl = p >> 18;
        int d  = (int)(p & 0x3FFFFu);
        int pos = atomicAdd(&degl[sl], 1);
        col[e0 + offl[sl] + pos] = d;
    }
}

// ---------------- weight conversion (transpose to bf16) ----------------
__global__ void convert_weights(const float* __restrict__ W1, const float* __restrict__ W2,
                                unsigned short* __restrict__ w1t, unsigned short* __restrict__ w2t) {
    int idx = blockIdx.x * blockDim.x + threadIdx.x;
    if (idx < FEAT_DIM * HID) {
        int k = idx / HID, n = idx % HID;
        w1t[(size_t)n * FEAT_DIM + k] = f2bf_rne(W1[idx]);
    } else {
        int j = idx - FEAT_DIM * HID;
        if (j < HID * DLAT) {
            int k = j / DLAT, n = j % DLAT;
            w2t[(size_t)n * HID + k] = f2bf_rne(W2[j]);
        }
    }
}

// ---------------- GEMM1: H = leakyrelu(feats @ W1 + b1), bf16 out ----------------
__launch_bounds__(512, 4)
__global__ void gemm1_kernel(const float* __restrict__ feats,
                             const unsigned short* __restrict__ w1t,
                             const float* __restrict__ b1,
                             unsigned short* __restrict__ H) {
    __shared__ __align__(16) unsigned char smem[65536];
    unsigned short* sA = (unsigned short*)smem;            // ushort units
    unsigned short* sB = (unsigned short*)(smem + 8192);
    unsigned short* sH = (unsigned short*)smem;

    const int t    = threadIdx.x;
    const int lane = t & 63;
    const int w    = t >> 6;        // 0..7
    const int wr   = w >> 2;        // 0..1: rows 64*wr
    const int wc   = w & 3;         // 0..3: cols 64*wc
    const int l15  = lane & 15;
    const int l4   = lane >> 4;
    const int item0 = blockIdx.x * 128;

    const int a_k4  = t >> 7;
    const int a_row = t & 127;
    const int a_rowg = min(item0 + a_row, NUM_ITEM - 1);
    const float* a_src = feats + (size_t)a_rowg * FEAT_DIM + a_k4 * 8;
    unsigned short* a_dst = sA + a_k4 * 1024 + a_row * 8;

    const int b_col = t & 255;
    const int b_kq  = (t >> 8) * 2;
    const unsigned short* b_src = w1t + (size_t)b_col * FEAT_DIM + b_kq * 8;
    unsigned short* b_dst = sB + b_kq * 2048 + b_col * 8;

    f32x4 acc[4][4];
    #pragma unroll
    for (int i = 0; i < 4; ++i)
        #pragma unroll
        for (int j = 0; j < 4; ++j) acc[i][j] = (f32x4)0.0f;

    for (int kk = 0; kk < 16; ++kk) {
        const int kbase = kk * 32;
        float4 f0 = *reinterpret_cast<const float4*>(a_src + kbase);
        float4 f1 = *reinterpret_cast<const float4*>(a_src + kbase + 4);
        BF8 ta;
        ta.u[0] = f2bf_rne(f0.x); ta.u[1] = f2bf_rne(f0.y);
        ta.u[2] = f2bf_rne(f0.z); ta.u[3] = f2bf_rne(f0.w);
        ta.u[4] = f2bf_rne(f1.x); ta.u[5] = f2bf_rne(f1.y);
        ta.u[6] = f2bf_rne(f1.z); ta.u[7] = f2bf_rne(f1.w);
        *reinterpret_cast<ushort8v*>(a_dst) = ta.u;
        ushort8v bv0 = *reinterpret_cast<const ushort8v*>(b_src + kbase);
        ushort8v bv1 = *reinterpret_cast<const ushort8v*>(b_src + kbase + 8);
        *reinterpret_cast<ushort8v*>(b_dst)        = bv0;
        *reinterpret_cast<ushort8v*>(b_dst + 2048) = bv1;
        __syncthreads();

        BF8 af[4];
        #pragma unroll
        for (int rf = 0; rf < 4; ++rf)
            af[rf].u = *reinterpret_cast<const ushort8v*>(sA + l4 * 1024 + (wr * 64 + rf * 16 + l15) * 8);
        #pragma unroll
        for (int cf = 0; cf < 4; ++cf) {
            BF8 bf;
            bf.u = *reinterpret_cast<const ushort8v*>(sB + l4 * 2048 + (wc * 64 + cf * 16 + l15) * 8);
            #pragma unroll
            for (int rf = 0; rf < 4; ++rf)
                acc[rf][cf] = __builtin_amdgcn_mfma_f32_16x16x32_bf16(af[rf].b, bf.b, acc[rf][cf], 0, 0, 0);
        }
        __syncthreads();
    }

    float bias[4];
    #pragma unroll
    for (int cf = 0; cf < 4; ++cf) bias[cf] = b1[wc * 64 + cf * 16 + l15];

    #pragma unroll
    for (int rf = 0; rf < 4; ++rf) {
        #pragma unroll
        for (int cf = 0; cf < 4; ++cf) {
            const int colc = wc * 64 + cf * 16 + l15;
            #pragma unroll
            for (int r = 0; r < 4; ++r) {
                const int row = wr * 64 + rf * 16 + l4 * 4 + r;
                float h = acc[rf][cf][r] + bias[cf];
                h = h > 0.0f ? h : 0.01f * h;
                sH[row * 256 + colc] = f2bf_rne(h);
            }
        }
    }
    __syncthreads();

    #pragma unroll
    for (int p = 0; p < 8; ++p) {
        const int idx  = p * 512 + t;     // 0..4095
        const int row  = idx >> 5;        // 0..127
        const int chnk = idx & 31;        // 8 ushorts each
        if (item0 + row < NUM_ITEM) {
            *reinterpret_cast<ushort8v*>(H + (size_t)(item0 + row) * HID + chnk * 8) =
                *reinterpret_cast<const ushort8v*>(sH + row * 256 + chnk * 8);
        }
    }
}

// ---------------- GEMM2: out_items = H @ W2 + b2 ; xs = bf16(dinv * out) ----------------
__launch_bounds__(256)
__global__ void gemm2_kernel(const unsigned short* __restrict__ H,
                             const unsigned short* __restrict__ w2t,
                             const float* __restrict__ b2,
                             const float* __restrict__ dinv,
                             float* __restrict__ out,
                             unsigned short* __restrict__ xs) {
    const int tid  = threadIdx.x;
    const int lane = tid & 63;
    const int w    = tid >> 6;
    const int l15  = lane & 15;
    const int l4   = lane >> 4;
    const int item0 = blockIdx.x * 64;

    const int rowg = min(item0 + w * 16 + l15, NUM_ITEM - 1);
    const unsigned short* hrow = H + (size_t)rowg * HID;

    f32x4 acc2[4];
    #pragma unroll
    for (int j = 0; j < 4; ++j) acc2[j] = (f32x4)0.0f;

    for (int kk = 0; kk < 8; ++kk) {
        const int kbase = kk * 32 + l4 * 8;
        BF8 ta;
        ta.u = *reinterpret_cast<const ushort8v*>(hrow + kbase);
        #pragma unroll
        for (int cf = 0; cf < 4; ++cf) {
            BF8 tb;
            tb.u = *reinterpret_cast<const ushort8v*>(w2t + (size_t)(cf * 16 + l15) * HID + kbase);
            acc2[cf] = __builtin_amdgcn_mfma_f32_16x16x32_bf16(ta.b, tb.b, acc2[cf], 0, 0, 0);
        }
    }

    #pragma unroll
    for (int cf = 0; cf < 4; ++cf) {
        const int colc = cf * 16 + l15;
        const float bias = b2[colc];
        #pragma unroll
        for (int r = 0; r < 4; ++r) {
            const int item = item0 + w * 16 + l4 * 4 + r;
            if (item < NUM_ITEM) {
                const int node = NUM_USER + item;
                float v = acc2[cf][r] + bias;
                out[(size_t)node * DLAT + colc] = v;
                xs [(size_t)node * DLAT + colc] = f2bf_rne(v * dinv[node]);
            }
        }
    }
}

// ---------------- user init: out = pref, xs = bf16(pref * dinv) ----------------
__global__ void pref_init(const float* __restrict__ pref, const float* __restrict__ dinv,
                          float* __restrict__ out, unsigned short* __restrict__ xs, int n4) {
    int i = blockIdx.x * blockDim.x + threadIdx.x;  // float4 index over NUM_USER*64/4
    if (i < n4) {
        float4 v = reinterpret_cast<const float4*>(pref)[i];
        float di = dinv[i >> 4];
        reinterpret_cast<float4*>(out)[i] = v;
        uint2 p;
        p.x = (unsigned)f2bf_rne(v.x * di) | ((unsigned)f2bf_rne(v.y * di) << 16);
        p.y = (unsigned)f2bf_rne(v.z * di) | ((unsigned)f2bf_rne(v.w * di) << 16);
        *reinterpret_cast<uint2*>(xs + (size_t)i * 4) = p;
    }
}

// ---------------- CSR gather hop (bf16 state): one wave per node ----------------
__launch_bounds__(256)
__global__ void hop_csr(const int* __restrict__ rowptr, const int* __restrict__ col,
                        const float* __restrict__ dinv, const unsigned short* __restrict__ xs,
                        float* __restrict__ out, unsigned short* __restrict__ xs_next,
                        int is_final, int n) {
    const int wave = (blockIdx.x * blockDim.x + threadIdx.x) >> 6;
    const int lane = threadIdx.x & 63;
    if (wave >= n) return;
    const int r0  = rowptr[wave];
    const int r1  = rowptr[wave + 1];
    const int g   = lane >> 4;
    const int r16 = lane & 15;

    float s0 = 0.0f, s1 = 0.0f, s2 = 0.0f, s3 = 0.0f;

    for (int base = r0; base < r1; base += 64) {
        int rem = r1 - base; if (rem > 64) rem = 64;
        int cvec = (lane < rem) ? col[base + lane] : 0;
        int j = 0;
        for (; j + 16 <= rem; j += 16) {
            int c0 = __shfl(cvec, j + g);
            int c1 = __shfl(cvec, j + 4 + g);
            int c2 = __shfl(cvec, j + 8 + g);
            int c3 = __shfl(cvec, j + 12 + g);
            uint2 v0 = *reinterpret_cast<const uint2*>(xs + (size_t)c0 * DLAT + 4 * r16);
            uint2 v1 = *reinterpret_cast<const uint2*>(xs + (size_t)c1 * DLAT + 4 * r16);
            uint2 v2 = *reinterpret_cast<const uint2*>(xs + (size_t)c2 * DLAT + 4 * r16);
            uint2 v3 = *reinterpret_cast<const uint2*>(xs + (size_t)c3 * DLAT + 4 * r16);
            s0 += bf_lo(v0.x); s1 += bf_hi(v0.x); s2 += bf_lo(v0.y); s3 += bf_hi(v0.y);
            s0 += bf_lo(v1.x); s1 += bf_hi(v1.x); s2 += bf_lo(v1.y); s3 += bf_hi(v1.y);
            s0 += bf_lo(v2.x); s1 += bf_hi(v2.x); s2 += bf_lo(v2.y); s3 += bf_hi(v2.y);
            s0 += bf_lo(v3.x); s1 += bf_hi(v3.x); s2 += bf_lo(v3.y); s3 += bf_hi(v3.y);
        }
        for (; j + 4 <= rem; j += 4) {
            int c = __shfl(cvec, j + g);
            uint2 v = *reinterpret_cast<const uint2*>(xs + (size_t)c * DLAT + 4 * r16);
            s0 += bf_lo(v.x); s1 += bf_hi(v.x); s2 += bf_lo(v.y); s3 += bf_hi(v.y);
        }
        int tail = rem - j;  // 0..3
        if (tail > 0) {
            int jj = j + g;
            int cj = __shfl(cvec, jj < rem ? jj : (rem - 1));
            if (jj < rem) {
                uint2 v = *reinterpret_cast<const uint2*>(xs + (size_t)cj * DLAT + 4 * r16);
                s0 += bf_lo(v.x); s1 += bf_hi(v.x); s2 += bf_lo(v.y); s3 += bf_hi(v.y);
            }
        }
    }

    s0 += __shfl_xor(s0, 16); s0 += __shfl_xor(s0, 32);
    s1 += __shfl_xor(s1, 16); s1 += __shfl_xor(s1, 32);
    s2 += __shfl_xor(s2, 16); s2 += __shfl_xor(s2, 32);
    s3 += __shfl_xor(s3, 16); s3 += __shfl_xor(s3, 32);

    if (g == 0) {
        float di = dinv[wave];
        float y0 = di * s0, y1 = di * s1, y2 = di * s2, y3 = di * s3;
        size_t o = (size_t)wave * DLAT + 4 * r16;
        float4 prev = *reinterpret_cast<const float4*>(out + o);
        if (is_final) {
            float4 wv;
            wv.x = (prev.x + y0) * (1.0f / 3.0f);
            wv.y = (prev.y + y1) * (1.0f / 3.0f);
            wv.z = (prev.z + y2) * (1.0f / 3.0f);
            wv.w = (prev.w + y3) * (1.0f / 3.0f);
            *reinterpret_cast<float4*>(out + o) = wv;
        } else {
            float4 wv;
            wv.x = prev.x + y0;
            wv.y = prev.y + y1;
            wv.z = prev.z + y2;
            wv.w = prev.w + y3;
            *reinterpret_cast<float4*>(out + o) = wv;
            uint2 p;
            p.x = (unsigned)f2bf_rne(di * y0) | ((unsigned)f2bf_rne(di * y1) << 16);
            p.y = (unsigned)f2bf_rne(di * y2) | ((unsigned)f2bf_rne(di * y3) << 16);
            *reinterpret_cast<uint2*>(xs_next + o) = p;
        }
    }
}

extern "C" void kernel_launch(void* const* d_in, const int* in_sizes, int n_in,
                              void* d_out, int out_size, void* d_ws, size_t ws_size,
                              hipStream_t stream) {
    const float* feats = (const float*)d_in[0];
    const int*   eidx  = (const int*)d_in[1];
    const float* pref  = (const float*)d_in[2];
    const float* W1    = (const float*)d_in[3];
    const float* b1    = (const float*)d_in[4];
    const float* W2    = (const float*)d_in[5];
    const float* b2    = (const float*)d_in[6];

    const int E = in_sizes[1] / 2;       // directed edges
    const int npair = E / 2;             // undirected pairs; row0 = [src_u | dst_i]
    const int* usrc = eidx;              // first npair entries of row 0
    const int* idst = eidx + npair;      // second npair entries of row 0 (= dst_i)

    char* ws = (char*)d_ws;
    size_t off = 0;
    auto alloc = [&](size_t bytes) -> void* {
        void* p = ws + off;
        off += (bytes + 255) & ~(size_t)255;
        return p;
    };
    const size_t xsbytes = (size_t)NUM_NODES * DLAT * sizeof(unsigned short);
    unsigned short* xsA = (unsigned short*)alloc(xsbytes);
    unsigned short* xsB = (unsigned short*)alloc(xsbytes);
    int*      colbf = (int*)alloc((size_t)E * sizeof(int));
    unsigned* pairs = (unsigned*)alloc((size_t)E * sizeof(unsigned));  // reused as H after csr_build
    float*    dinv  = (float*)alloc((size_t)NUM_NODES * sizeof(float));
    int*      rowp  = (int*)alloc((size_t)(NUM_NODES + 1) * sizeof(int));
    int*      bhist = (int*)alloc((size_t)NBUCK * sizeof(int));
    int*      bbase = (int*)alloc((size_t)NBUCK * sizeof(int));
    int*      gfill = (int*)alloc((size_t)NBUCK * sizeof(int));
    unsigned short* w1t = (unsigned short*)alloc((size_t)FEAT_DIM * HID * 2);
    unsigned short* w2t = (unsigned short*)alloc((size_t)HID * DLAT * 2);
    float* out = (float*)d_out;
    unsigned short* H = (unsigned short*)pairs;  // 50000*256*2 = 25.6 MB == E*4

    // bucketed CSR build (pairs processed once; each emits both directions)
    hipMemsetAsync(bhist, 0, (size_t)NBUCK * sizeof(int), stream);
    hipMemsetAsync(gfill, 0, (size_t)NBUCK * sizeof(int), stream);
    bucket_hist2<<<512, 256, 0, stream>>>(usrc, idst, bhist, npair);
    bucket_scan<<<1, 512, 0, stream>>>(bhist, bbase);
    bucket_scatter2<<<(npair + CPAIR - 1) / CPAIR, 256, 0, stream>>>(usrc, idst, bbase, gfill, pairs, npair);
    csr_build<<<NBUCK, 256, 0, stream>>>(bhist, bbase, pairs, rowp, dinv, colbf);

    // weights -> bf16 transposed
    convert_weights<<<(FEAT_DIM * HID + HID * DLAT + 255) / 256, 256, 0, stream>>>(W1, W2, w1t, w2t);

    // item MLP as two tiled GEMMs (H overlays pairs, which is dead after csr_build)
    gemm1_kernel<<<(NUM_ITEM + 127) / 128, 512, 0, stream>>>(feats, w1t, b1, H);
    gemm2_kernel<<<(NUM_ITEM + 63) / 64, 256, 0, stream>>>(H, w2t, b2, dinv, out, xsA);
    pref_init<<<(NUM_USER * DLAT / 4 + 255) / 256, 256, 0, stream>>>(pref, dinv, out, xsA, NUM_USER * DLAT / 4);

    // hop 1: y1 = dinv * (A xsA); out += y1; xsB = bf16(dinv * y1)
    const int hopBlocks = (NUM_NODES * 64 + 255) / 256;
    hop_csr<<<hopBlocks, 256, 0, stream>>>(rowp, colbf, dinv, xsA, out, xsB, 0, NUM_NODES);

    // hop 2: y2 = dinv * (A xsB); out = (out + y2) / 3
    hop_csr<<<hopBlocks, 256, 0, stream>>>(rowp, colbf, dinv, xsB, out, nullptr, 1, NUM_NODES);
}